// Round 5
// baseline (246.564 us; speedup 1.0000x reference)
//
#include <hip/hip_runtime.h>

// One wave (64 lanes) per batch element. State: 1024 complex amps = 16/lane
// in registers (re[16], im[16]). s = lane*16 + r ; qubit q <-> s-bit (9-q).
// Bits 0..3 (qubits 6..9): in-register pairs. Bits 4..9 (qubits 0..5):
// cross-lane via __shfl_xor. No LDS, no __syncthreads.
//
// R1: (256,4) 64-VGPR cap -> full spill, 462us.
// R2: (256,2) 128 cap, spills ~290MB, 180us.
// R3: (256,1) 196 VGPR no-spill, 1 wave/SIMD latency-bound, 208us.
// R4: (256,2)+SGPR uniforms: still pinned 128 + ~270MB spill, 167us.
//     Diagnosis: scheduler hoists many gates' matrix computations (all
//     derive from early-available SGPRs) -> ~196-reg live set.
// R5: sched_barrier(0) between gates forbids cross-gate hoisting; encoding
//     phase replaced by closed-form product state fused with ZZ phase
//     (kills 10 gates / 40 sincos / 192 shuffles).

__device__ __forceinline__ float wred(float v) {
  v += __shfl_xor(v, 1);
  v += __shfl_xor(v, 2);
  v += __shfl_xor(v, 4);
  v += __shfl_xor(v, 8);
  v += __shfl_xor(v, 16);
  v += __shfl_xor(v, 32);
  return v;
}

// force a wave-uniform float into an SGPR
__device__ __forceinline__ float rfl(float x) {
  return __int_as_float(__builtin_amdgcn_readfirstlane(__float_as_int(x)));
}

// tanh(x) = 1 - 2/(exp(2x)+1); __expf saturates correctly at +-inf
__device__ __forceinline__ float fast_tanh(float x) {
  return 1.0f - 2.0f / (__expf(2.0f * x) + 1.0f);
}

#define SB() __builtin_amdgcn_sched_barrier(0)

template<int BIT>
__device__ __forceinline__ void gate_apply(float (&re)[16], float (&im)[16], int lane,
    float m00r, float m00i, float m01r, float m01i,
    float m10r, float m10i, float m11r, float m11i) {
  if constexpr (BIT < 4) {
    #pragma unroll
    for (int r0 = 0; r0 < 16; ++r0) {
      if ((r0 & (1 << BIT)) == 0) {
        const int r1 = r0 | (1 << BIT);
        const float a0r = re[r0], a0i = im[r0], a1r = re[r1], a1i = im[r1];
        re[r0] = m00r*a0r - m00i*a0i + m01r*a1r - m01i*a1i;
        im[r0] = m00r*a0i + m00i*a0r + m01r*a1i + m01i*a1r;
        re[r1] = m10r*a0r - m10i*a0i + m11r*a1r - m11i*a1i;
        im[r1] = m10r*a0i + m10i*a0r + m11r*a1i + m11i*a1r;
      }
    }
  } else {
    const int lm = 1 << (BIT - 4);
    const bool hi = (lane & lm) != 0;
    // own-amp coeff / partner-amp coeff selected once per gate
    const float cAr = hi ? m11r : m00r, cAi = hi ? m11i : m00i;
    const float cBr = hi ? m10r : m01r, cBi = hi ? m10i : m01i;
    #pragma unroll
    for (int r = 0; r < 16; ++r) {
      const float pr = __shfl_xor(re[r], lm);
      const float pi = __shfl_xor(im[r], lm);
      const float ar = re[r], ai = im[r];
      re[r] = cAr*ar - cAi*ai + cBr*pr - cBi*pi;
      im[r] = cAr*ai + cAi*ar + cBr*pi + cBi*pr;
    }
  }
}

// new[s] = old[ s ^ (ctrlbit(s) ? tgtmask : 0) ]
template<int CB, int TB>
__device__ __forceinline__ void cnot_apply(float (&re)[16], float (&im)[16], int lane) {
  if constexpr (CB >= 4 && TB >= 4) {
    const bool c1 = (lane & (1 << (CB - 4))) != 0;
    #pragma unroll
    for (int r = 0; r < 16; ++r) {
      const float pr = __shfl_xor(re[r], 1 << (TB - 4));
      const float pi = __shfl_xor(im[r], 1 << (TB - 4));
      re[r] = c1 ? pr : re[r];
      im[r] = c1 ? pi : im[r];
    }
  } else if constexpr (CB >= 4 && TB < 4) {
    const bool c1 = (lane & (1 << (CB - 4))) != 0;
    #pragma unroll
    for (int r0 = 0; r0 < 16; ++r0) {
      if ((r0 & (1 << TB)) == 0) {
        const int r1 = r0 | (1 << TB);
        const float ar = re[r0], br = re[r1];
        re[r0] = c1 ? br : ar;  re[r1] = c1 ? ar : br;
        const float ai = im[r0], bi = im[r1];
        im[r0] = c1 ? bi : ai;  im[r1] = c1 ? ai : bi;
      }
    }
  } else if constexpr (CB < 4 && TB >= 4) {
    #pragma unroll
    for (int r = 0; r < 16; ++r) {
      if ((r & (1 << CB)) != 0) {     // compile-time per unrolled r
        re[r] = __shfl_xor(re[r], 1 << (TB - 4));
        im[r] = __shfl_xor(im[r], 1 << (TB - 4));
      }
    }
  } else {
    #pragma unroll
    for (int r0 = 0; r0 < 16; ++r0) {
      if ((r0 & (1 << CB)) != 0 && (r0 & (1 << TB)) == 0) {
        const int r1 = r0 | (1 << TB);
        float t = re[r0]; re[r0] = re[r1]; re[r1] = t;
        t = im[r0]; im[r0] = im[r1]; im[r1] = t;
      }
    }
  }
}

// half_ang(s) = 0.5*pi * sum_p J_p * mask_p(s),  mask = +1 iff bits differ = -z_i z_j
// decomposed: C(lane) [high-high] + d[j]*z_j(r) [high-low] + e[ij]*z_i(r)z_j(r) [low-low]
template<int I, int J>
__device__ __forceinline__ void pair_accum(float t, int lane, float& Cc,
                                           float (&dcf)[4], float (&ecf)[6]) {
  if constexpr (J <= 5) {
    const bool diff = (((lane >> (5 - I)) ^ (lane >> (5 - J))) & 1) != 0;
    Cc += diff ? -t : t;            // t * z_i(lane) * z_j(lane)
  } else if constexpr (I <= 5) {
    const bool b = ((lane >> (5 - I)) & 1) != 0;
    dcf[J - 6] += b ? -t : t;       // t * z_i(lane)
  } else {
    constexpr int eb = (I == 6) ? 0 : (I == 7) ? 3 : 5;
    ecf[eb + (J - I - 1)] = rfl(t); // wave-uniform -> SGPR
  }
}

#define PAIR(i, j) { \
  float dot_ = y0[i]*y0[j] + y1[i]*y1[j]; \
  dot_ = wred(dot_) * (1.0f/127.0f); \
  const float t_ = -1.5707963267948966f * fast_tanh(dot_ * expA); \
  pair_accum<i, j>(t_, lane, Cc, dcoef, ecoef); }

// layer-0 Rot: M = RZ(w2) RY(w1) RZ(w0)
#define ROT0(q) { \
  const float w0 = vw[(q)*3+0], w1 = vw[(q)*3+1], w2 = vw[(q)*3+2]; \
  float cy, sy; __sincosf(0.5f*w1, &sy, &cy); \
  float ca, sa; __sincosf(0.5f*(w0+w2), &sa, &ca); \
  float cb, sb; __sincosf(0.5f*(w0-w2), &sb, &cb); \
  gate_apply<9 - (q)>(re, im, lane, \
      cy*ca, -cy*sa,  -sy*cb, -sy*sb, \
      sy*cb, -sy*sb,   cy*ca,  cy*sa); } SB();

// fused: EncHalf (RZ(phi/2)RY(theta/2)) followed by layer-l Rot  ->  M = R * E
#define MERGED(l, q) { \
  float cy, sy; __sincosf(0.25f * th[q], &sy, &cy); \
  float cz, sz; __sincosf(0.25f * ph[q], &sz, &cz); \
  const float e00r =  cy*cz, e00i = -cy*sz, e01r = -sy*cz, e01i =  sy*sz; \
  const float e10r =  sy*cz, e10i =  sy*sz, e11r =  cy*cz, e11i =  cy*sz; \
  const float w0 = vw[((l)*10+(q))*3+0], w1 = vw[((l)*10+(q))*3+1], w2 = vw[((l)*10+(q))*3+2]; \
  float cY, sY; __sincosf(0.5f*w1, &sY, &cY); \
  float ca, sa; __sincosf(0.5f*(w0+w2), &sa, &ca); \
  float cb, sb; __sincosf(0.5f*(w0-w2), &sb, &cb); \
  const float r00r =  cY*ca, r00i = -cY*sa, r01r = -sY*cb, r01i = -sY*sb; \
  const float r10r =  sY*cb, r10i = -sY*sb, r11r =  cY*ca, r11i =  cY*sa; \
  const float m00r = r00r*e00r - r00i*e00i + r01r*e10r - r01i*e10i; \
  const float m00i = r00r*e00i + r00i*e00r + r01r*e10i + r01i*e10r; \
  const float m01r = r00r*e01r - r00i*e01i + r01r*e11r - r01i*e11i; \
  const float m01i = r00r*e01i + r00i*e01r + r01r*e11i + r01i*e11r; \
  const float m10r = r10r*e00r - r10i*e00i + r11r*e10r - r11i*e10i; \
  const float m10i = r10r*e00i + r10i*e00r + r11r*e10i + r11i*e10r; \
  const float m11r = r10r*e01r - r10i*e01i + r11r*e11r - r11i*e11i; \
  const float m11i = r10r*e01i + r10i*e01r + r11r*e11i + r11i*e11r; \
  gate_apply<9 - (q)>(re, im, lane, m00r, m00i, m01r, m01i, m10r, m10i, m11r, m11i); } SB();

#define CNOT(ctrl, rng) cnot_apply<9 - (ctrl), 9 - ((((ctrl) + (rng)) % 10))>(re, im, lane); SB();

extern "C" __global__ void __launch_bounds__(256, 2)
qhl_kernel(const float* __restrict__ c_kt, const float* __restrict__ dc_kt,
           const float* __restrict__ vw,  const float* __restrict__ w_proj,
           const float* __restrict__ b_proj, const float* __restrict__ log_alpha,
           float* __restrict__ out) {
  const int wave = threadIdx.x >> 6;
  const int lane = threadIdx.x & 63;
  const int bid  = blockIdx.x * 4 + wave;

  const float* c   = c_kt  + (size_t)bid * 1280;
  const float* dcp = dc_kt + (size_t)bid * 1280;

  // ---- correlation: rows held in registers, stats via wave reductions ----
  // row stride 10 floats = 40B = 8B-aligned -> float2 loads (5 per row)
  float y0[10], y1[10];
  {
    const float2* c0 = (const float2*)(c   + lane * 10);
    const float2* d0 = (const float2*)(dcp + lane * 10);
    const float2* c1 = (const float2*)(c   + (lane + 64) * 10);
    const float2* d1 = (const float2*)(dcp + (lane + 64) * 10);
    #pragma unroll
    for (int k = 0; k < 5; ++k) {
      const float2 a0 = c0[k], b0 = d0[k], a1 = c1[k], b1 = d1[k];
      y0[2*k]   = a0.x + 0.5f * b0.x;  y0[2*k+1] = a0.y + 0.5f * b0.y;
      y1[2*k]   = a1.x + 0.5f * b1.x;  y1[2*k+1] = a1.y + 0.5f * b1.y;
    }
  }
  #pragma unroll
  for (int k = 0; k < 10; ++k) {
    const float mean = wred(y0[k] + y1[k]) * (1.0f / 128.0f);
    y0[k] -= mean; y1[k] -= mean;
    const float ss = wred(y0[k]*y0[k] + y1[k]*y1[k]);
    // rs = 1 / max(sqrt(ss/127), 1e-8)
    const float rs = fminf(__builtin_amdgcn_rsqf(ss * (1.0f / 127.0f)), 1e8f);
    y0[k] *= rs; y1[k] *= rs;
  }

  const float expA = rfl(__expf(log_alpha[0]));
  float Cc = 0.0f, dcoef[4] = {0, 0, 0, 0}, ecoef[6];
  PAIR(0,1) PAIR(0,2) PAIR(0,3) PAIR(0,4) PAIR(0,5) PAIR(0,6) PAIR(0,7) PAIR(0,8) PAIR(0,9)
  PAIR(1,2) PAIR(1,3) PAIR(1,4) PAIR(1,5) PAIR(1,6) PAIR(1,7) PAIR(1,8) PAIR(1,9)
  PAIR(2,3) PAIR(2,4) PAIR(2,5) PAIR(2,6) PAIR(2,7) PAIR(2,8) PAIR(2,9)
  PAIR(3,4) PAIR(3,5) PAIR(3,6) PAIR(3,7) PAIR(3,8) PAIR(3,9)
  PAIR(4,5) PAIR(4,6) PAIR(4,7) PAIR(4,8) PAIR(4,9)
  PAIR(5,6) PAIR(5,7) PAIR(5,8) PAIR(5,9)
  PAIR(6,7) PAIR(6,8) PAIR(6,9)
  PAIR(7,8) PAIR(7,9)
  PAIR(8,9)

  // ---- encoding angles: wave-uniform -> force into SGPRs ----
  float th[10], ph[10];
  #pragma unroll
  for (int q = 0; q < 10; ++q) {
    th[q] = rfl(c[1270 + q]);
    ph[q] = rfl(dcp[1270 + q]);
  }
  SB();

  // ---- closed-form initial state: (prod_q RZ(ph)RY(th)|0>) * e^{i h} ----
  // single-qubit: RZ(ph)RY(th)|0> = (cos(th/2) e^{-i ph/2}, sin(th/2) e^{+i ph/2})
  // qubits 0..5 <-> lane bits 5..0 (product -> L, per lane)
  // qubits 6..9 <-> r bits 3..0    (product -> R[r], via tables a[4][2])
  float re[16], im[16];
  {
    float Lr = 1.0f, Li = 0.0f;
    #pragma unroll
    for (int q = 0; q < 6; ++q) {
      float cy, sy; __sincosf(0.5f * th[q], &sy, &cy);
      float cz, sz; __sincosf(0.5f * ph[q], &sz, &cz);
      const bool b = ((lane >> (5 - q)) & 1) != 0;
      const float zr = b ? sy * cz : cy * cz;
      const float zi = b ? sy * sz : -cy * sz;
      const float nr = Lr * zr - Li * zi;
      Li = Lr * zi + Li * zr;
      Lr = nr;
    }
    float ar[4][2], ai[4][2];
    #pragma unroll
    for (int t = 0; t < 4; ++t) {
      float cy, sy; __sincosf(0.5f * th[6 + t], &sy, &cy);
      float cz, sz; __sincosf(0.5f * ph[6 + t], &sz, &cz);
      ar[t][0] = cy * cz;  ai[t][0] = -cy * sz;
      ar[t][1] = sy * cz;  ai[t][1] =  sy * sz;
    }
    #pragma unroll
    for (int r = 0; r < 16; ++r) {
      const int b3 = (r >> 3) & 1, b2 = (r >> 2) & 1, b1 = (r >> 1) & 1, b0 = r & 1;
      // R = a0[b3]*a1[b2]*a2[b1]*a3[b0]
      float Rr = ar[0][b3], Ri = ai[0][b3];
      float t1 = Rr * ar[1][b2] - Ri * ai[1][b2];
      Ri = Rr * ai[1][b2] + Ri * ar[1][b2]; Rr = t1;
      t1 = Rr * ar[2][b1] - Ri * ai[2][b1];
      Ri = Rr * ai[2][b1] + Ri * ar[2][b1]; Rr = t1;
      t1 = Rr * ar[3][b0] - Ri * ai[3][b0];
      Ri = Rr * ai[3][b0] + Ri * ar[3][b0]; Rr = t1;
      // ZZ phase angle
      float h = Cc;
      h += b3 ? -dcoef[0] : dcoef[0];
      h += b2 ? -dcoef[1] : dcoef[1];
      h += b1 ? -dcoef[2] : dcoef[2];
      h += b0 ? -dcoef[3] : dcoef[3];
      h += (b3 ^ b2) ? -ecoef[0] : ecoef[0];
      h += (b3 ^ b1) ? -ecoef[1] : ecoef[1];
      h += (b3 ^ b0) ? -ecoef[2] : ecoef[2];
      h += (b2 ^ b1) ? -ecoef[3] : ecoef[3];
      h += (b2 ^ b0) ? -ecoef[4] : ecoef[4];
      h += (b1 ^ b0) ? -ecoef[5] : ecoef[5];
      float sn, cs; __sincosf(h, &sn, &cs);
      // state = e^{ih} * L * R
      const float pr = cs * Lr - sn * Li;
      const float pi = cs * Li + sn * Lr;
      re[r] = pr * Rr - pi * Ri;
      im[r] = pr * Ri + pi * Rr;
    }
  }
  SB();

  // ---- layer 0 ----
  ROT0(0) ROT0(1) ROT0(2) ROT0(3) ROT0(4) ROT0(5) ROT0(6) ROT0(7) ROT0(8) ROT0(9)
  CNOT(0,1) CNOT(1,1) CNOT(2,1) CNOT(3,1) CNOT(4,1)
  CNOT(5,1) CNOT(6,1) CNOT(7,1) CNOT(8,1) CNOT(9,1)
  // ---- re-encode(0.5) fused with layer-1 Rot ----
  MERGED(1,0) MERGED(1,1) MERGED(1,2) MERGED(1,3) MERGED(1,4)
  MERGED(1,5) MERGED(1,6) MERGED(1,7) MERGED(1,8) MERGED(1,9)
  CNOT(0,2) CNOT(1,2) CNOT(2,2) CNOT(3,2) CNOT(4,2)
  CNOT(5,2) CNOT(6,2) CNOT(7,2) CNOT(8,2) CNOT(9,2)
  // ---- re-encode(0.5) fused with layer-2 Rot ----
  MERGED(2,0) MERGED(2,1) MERGED(2,2) MERGED(2,3) MERGED(2,4)
  MERGED(2,5) MERGED(2,6) MERGED(2,7) MERGED(2,8) MERGED(2,9)
  CNOT(0,3) CNOT(1,3) CNOT(2,3) CNOT(3,3) CNOT(4,3)
  CNOT(5,3) CNOT(6,3) CNOT(7,3) CNOT(8,3) CNOT(9,3)

  // ---- measurement: Z expvals then 3-action projection ----
  float P = 0.0f, e6 = 0.0f, e7 = 0.0f, e8 = 0.0f, e9 = 0.0f;
  #pragma unroll
  for (int r = 0; r < 16; ++r) {
    const float pp = re[r]*re[r] + im[r]*im[r];
    P  += pp;
    e6 += (r & 8) ? -pp : pp;
    e7 += (r & 4) ? -pp : pp;
    e8 += (r & 2) ? -pp : pp;
    e9 += (r & 1) ? -pp : pp;
  }
  float ev[10];
  ev[0] = (lane & 32) ? -P : P;
  ev[1] = (lane & 16) ? -P : P;
  ev[2] = (lane &  8) ? -P : P;
  ev[3] = (lane &  4) ? -P : P;
  ev[4] = (lane &  2) ? -P : P;
  ev[5] = (lane &  1) ? -P : P;
  ev[6] = e6; ev[7] = e7; ev[8] = e8; ev[9] = e9;
  #pragma unroll
  for (int i = 0; i < 10; ++i) ev[i] = wred(ev[i]);

  if (lane < 3) {
    float acc = b_proj[lane];
    #pragma unroll
    for (int i = 0; i < 10; ++i) acc += w_proj[lane * 10 + i] * ev[i];
    out[(size_t)bid * 3 + lane] = acc;
  }
}

extern "C" void kernel_launch(void* const* d_in, const int* in_sizes, int n_in,
                              void* d_out, int out_size, void* d_ws, size_t ws_size,
                              hipStream_t stream) {
  (void)in_sizes; (void)n_in; (void)d_ws; (void)ws_size; (void)out_size;
  const float* c_kt      = (const float*)d_in[0];
  const float* dc_kt     = (const float*)d_in[1];
  const float* vw        = (const float*)d_in[2];
  const float* w_proj    = (const float*)d_in[3];
  const float* b_proj    = (const float*)d_in[4];
  const float* log_alpha = (const float*)d_in[5];
  float* out = (float*)d_out;
  // 4096 batch elems, 1 wave each, 4 waves per 256-thread block
  qhl_kernel<<<dim3(1024), dim3(256), 0, stream>>>(c_kt, dc_kt, vw, w_proj,
                                                   b_proj, log_alpha, out);
}

// Round 6
// 192.189 us; speedup vs baseline: 1.2829x; 1.2829x over previous
//
#include <hip/hip_runtime.h>

// One wave (64 lanes) per batch element. State: 1024 complex amps = 16/lane
// in registers (re[16], im[16]). s = lane*16 + r ; qubit q <-> s-bit (9-q).
// Bits 0..3 (qubits 6..9): in-register pairs. Bits 4..9 (qubits 0..5):
// cross-lane via __shfl_xor. No LDS, no __syncthreads.
//
// R1: (256,4) 64-VGPR cap -> full spill, 462us.
// R2: (256,2) 128 cap, spills ~290MB, 180us.
// R3: (256,1) 196 VGPR no-spill, ~1 wave/SIMD latency-bound, 208us.
// R4: (256,2)+SGPR th/ph: still pinned 128 + ~270MB spill, 167us.
// R5: sched_barrier(0) everywhere: spills WORSE (480MB, 184us) - barriers
//     also block the scheduler's own pressure reduction. Reverted.
// R6: the fix for the actual cause: wave-uniform gate-matrix coefficients
//     were VALU-computed -> VGPRs. readfirstlane each one into the SGPR
//     file (SGPR_Count was only 64/102 used), so batched gate coeffs cost
//     scalar regs, not vector regs. Per-lane live set: re/im(32) + one
//     gate's shuffle temps(32) + misc ~= 80 < 128.

__device__ __forceinline__ float wred(float v) {
  v += __shfl_xor(v, 1);
  v += __shfl_xor(v, 2);
  v += __shfl_xor(v, 4);
  v += __shfl_xor(v, 8);
  v += __shfl_xor(v, 16);
  v += __shfl_xor(v, 32);
  return v;
}

// force a wave-uniform float into an SGPR
__device__ __forceinline__ float rfl(float x) {
  return __int_as_float(__builtin_amdgcn_readfirstlane(__float_as_int(x)));
}

// tanh(x) = 1 - 2/(exp(2x)+1); __expf saturates correctly at +-inf
__device__ __forceinline__ float fast_tanh(float x) {
  return 1.0f - 2.0f / (__expf(2.0f * x) + 1.0f);
}

template<int BIT>
__device__ __forceinline__ void gate_apply(float (&re)[16], float (&im)[16], int lane,
    float m00r, float m00i, float m01r, float m01i,
    float m10r, float m10i, float m11r, float m11i) {
  if constexpr (BIT < 4) {
    #pragma unroll
    for (int r0 = 0; r0 < 16; ++r0) {
      if ((r0 & (1 << BIT)) == 0) {
        const int r1 = r0 | (1 << BIT);
        const float a0r = re[r0], a0i = im[r0], a1r = re[r1], a1i = im[r1];
        re[r0] = m00r*a0r - m00i*a0i + m01r*a1r - m01i*a1i;
        im[r0] = m00r*a0i + m00i*a0r + m01r*a1i + m01i*a1r;
        re[r1] = m10r*a0r - m10i*a0i + m11r*a1r - m11i*a1i;
        im[r1] = m10r*a0i + m10i*a0r + m11r*a1i + m11i*a1r;
      }
    }
  } else {
    const int lm = 1 << (BIT - 4);
    const bool hi = (lane & lm) != 0;
    // own-amp coeff / partner-amp coeff selected once per gate
    const float cAr = hi ? m11r : m00r, cAi = hi ? m11i : m00i;
    const float cBr = hi ? m10r : m01r, cBi = hi ? m10i : m01i;
    #pragma unroll
    for (int r = 0; r < 16; ++r) {
      const float pr = __shfl_xor(re[r], lm);
      const float pi = __shfl_xor(im[r], lm);
      const float ar = re[r], ai = im[r];
      re[r] = cAr*ar - cAi*ai + cBr*pr - cBi*pi;
      im[r] = cAr*ai + cAi*ar + cBr*pi + cBi*pr;
    }
  }
}

// new[s] = old[ s ^ (ctrlbit(s) ? tgtmask : 0) ]
template<int CB, int TB>
__device__ __forceinline__ void cnot_apply(float (&re)[16], float (&im)[16], int lane) {
  if constexpr (CB >= 4 && TB >= 4) {
    const bool c1 = (lane & (1 << (CB - 4))) != 0;
    #pragma unroll
    for (int r = 0; r < 16; ++r) {
      const float pr = __shfl_xor(re[r], 1 << (TB - 4));
      const float pi = __shfl_xor(im[r], 1 << (TB - 4));
      re[r] = c1 ? pr : re[r];
      im[r] = c1 ? pi : im[r];
    }
  } else if constexpr (CB >= 4 && TB < 4) {
    const bool c1 = (lane & (1 << (CB - 4))) != 0;
    #pragma unroll
    for (int r0 = 0; r0 < 16; ++r0) {
      if ((r0 & (1 << TB)) == 0) {
        const int r1 = r0 | (1 << TB);
        const float ar = re[r0], br = re[r1];
        re[r0] = c1 ? br : ar;  re[r1] = c1 ? ar : br;
        const float ai = im[r0], bi = im[r1];
        im[r0] = c1 ? bi : ai;  im[r1] = c1 ? ai : bi;
      }
    }
  } else if constexpr (CB < 4 && TB >= 4) {
    #pragma unroll
    for (int r = 0; r < 16; ++r) {
      if ((r & (1 << CB)) != 0) {     // compile-time per unrolled r
        re[r] = __shfl_xor(re[r], 1 << (TB - 4));
        im[r] = __shfl_xor(im[r], 1 << (TB - 4));
      }
    }
  } else {
    #pragma unroll
    for (int r0 = 0; r0 < 16; ++r0) {
      if ((r0 & (1 << CB)) != 0 && (r0 & (1 << TB)) == 0) {
        const int r1 = r0 | (1 << TB);
        float t = re[r0]; re[r0] = re[r1]; re[r1] = t;
        t = im[r0]; im[r0] = im[r1]; im[r1] = t;
      }
    }
  }
}

// half_ang(s) = 0.5*pi * sum_p J_p * mask_p(s),  mask = +1 iff bits differ = -z_i z_j
// decomposed: C(lane) [high-high] + d[j]*z_j(r) [high-low] + e[ij]*z_i(r)z_j(r) [low-low]
template<int I, int J>
__device__ __forceinline__ void pair_accum(float t, int lane, float& Cc,
                                           float (&dcf)[4], float (&ecf)[6]) {
  if constexpr (J <= 5) {
    const bool diff = (((lane >> (5 - I)) ^ (lane >> (5 - J))) & 1) != 0;
    Cc += diff ? -t : t;            // t * z_i(lane) * z_j(lane)
  } else if constexpr (I <= 5) {
    const bool b = ((lane >> (5 - I)) & 1) != 0;
    dcf[J - 6] += b ? -t : t;       // t * z_i(lane)
  } else {
    constexpr int eb = (I == 6) ? 0 : (I == 7) ? 3 : 5;
    ecf[eb + (J - I - 1)] = rfl(t); // wave-uniform -> SGPR
  }
}

#define PAIR(i, j) { \
  float dot_ = y0[i]*y0[j] + y1[i]*y1[j]; \
  dot_ = wred(dot_) * (1.0f/127.0f); \
  const float t_ = -1.5707963267948966f * fast_tanh(dot_ * expA); \
  pair_accum<i, j>(t_, lane, Cc, dcoef, ecoef); }

// layer-0 Rot: M = RZ(w2) RY(w1) RZ(w0). All coeffs wave-uniform -> SGPRs.
#define ROT0(q) { \
  const float w0 = vw[(q)*3+0], w1 = vw[(q)*3+1], w2 = vw[(q)*3+2]; \
  float cy, sy; __sincosf(0.5f*w1, &sy, &cy); \
  float ca, sa; __sincosf(0.5f*(w0+w2), &sa, &ca); \
  float cb, sb; __sincosf(0.5f*(w0-w2), &sb, &cb); \
  gate_apply<9 - (q)>(re, im, lane, \
      rfl(cy*ca), rfl(-cy*sa),  rfl(-sy*cb), rfl(-sy*sb), \
      rfl(sy*cb), rfl(-sy*sb),  rfl( cy*ca), rfl( cy*sa)); }

// fused: EncHalf (RZ(phi/2)RY(theta/2)) followed by layer-l Rot  ->  M = R * E
// All 8 matrix elements wave-uniform -> SGPRs.
#define MERGED(l, q) { \
  float cy, sy; __sincosf(0.25f * th[q], &sy, &cy); \
  float cz, sz; __sincosf(0.25f * ph[q], &sz, &cz); \
  const float e00r =  cy*cz, e00i = -cy*sz, e01r = -sy*cz, e01i =  sy*sz; \
  const float e10r =  sy*cz, e10i =  sy*sz, e11r =  cy*cz, e11i =  cy*sz; \
  const float w0 = vw[((l)*10+(q))*3+0], w1 = vw[((l)*10+(q))*3+1], w2 = vw[((l)*10+(q))*3+2]; \
  float cY, sY; __sincosf(0.5f*w1, &sY, &cY); \
  float ca, sa; __sincosf(0.5f*(w0+w2), &sa, &ca); \
  float cb, sb; __sincosf(0.5f*(w0-w2), &sb, &cb); \
  const float r00r =  cY*ca, r00i = -cY*sa, r01r = -sY*cb, r01i = -sY*sb; \
  const float r10r =  sY*cb, r10i = -sY*sb, r11r =  cY*ca, r11i =  cY*sa; \
  gate_apply<9 - (q)>(re, im, lane, \
      rfl(r00r*e00r - r00i*e00i + r01r*e10r - r01i*e10i), \
      rfl(r00r*e00i + r00i*e00r + r01r*e10i + r01i*e10r), \
      rfl(r00r*e01r - r00i*e01i + r01r*e11r - r01i*e11i), \
      rfl(r00r*e01i + r00i*e01r + r01r*e11i + r01i*e11r), \
      rfl(r10r*e00r - r10i*e00i + r11r*e10r - r11i*e10i), \
      rfl(r10r*e00i + r10i*e00r + r11r*e10i + r11i*e10r), \
      rfl(r10r*e01r - r10i*e01i + r11r*e11r - r11i*e11i), \
      rfl(r10r*e01i + r10i*e01r + r11r*e11i + r11i*e11r)); }

#define CNOT(ctrl, rng) cnot_apply<9 - (ctrl), 9 - ((((ctrl) + (rng)) % 10))>(re, im, lane);

extern "C" __global__ void __launch_bounds__(256, 2)
qhl_kernel(const float* __restrict__ c_kt, const float* __restrict__ dc_kt,
           const float* __restrict__ vw,  const float* __restrict__ w_proj,
           const float* __restrict__ b_proj, const float* __restrict__ log_alpha,
           float* __restrict__ out) {
  const int wave = threadIdx.x >> 6;
  const int lane = threadIdx.x & 63;
  const int bid  = blockIdx.x * 4 + wave;

  const float* c   = c_kt  + (size_t)bid * 1280;
  const float* dcp = dc_kt + (size_t)bid * 1280;

  // ---- correlation: rows held in registers, stats via wave reductions ----
  // row stride 10 floats = 40B = 8B-aligned -> float2 loads (5 per row)
  float y0[10], y1[10];
  {
    const float2* c0 = (const float2*)(c   + lane * 10);
    const float2* d0 = (const float2*)(dcp + lane * 10);
    const float2* c1 = (const float2*)(c   + (lane + 64) * 10);
    const float2* d1 = (const float2*)(dcp + (lane + 64) * 10);
    #pragma unroll
    for (int k = 0; k < 5; ++k) {
      const float2 a0 = c0[k], b0 = d0[k], a1 = c1[k], b1 = d1[k];
      y0[2*k]   = a0.x + 0.5f * b0.x;  y0[2*k+1] = a0.y + 0.5f * b0.y;
      y1[2*k]   = a1.x + 0.5f * b1.x;  y1[2*k+1] = a1.y + 0.5f * b1.y;
    }
  }
  #pragma unroll
  for (int k = 0; k < 10; ++k) {
    const float mean = wred(y0[k] + y1[k]) * (1.0f / 128.0f);
    y0[k] -= mean; y1[k] -= mean;
    const float ss = wred(y0[k]*y0[k] + y1[k]*y1[k]);
    // rs = 1 / max(sqrt(ss/127), 1e-8)
    const float rs = fminf(__builtin_amdgcn_rsqf(ss * (1.0f / 127.0f)), 1e8f);
    y0[k] *= rs; y1[k] *= rs;
  }

  const float expA = rfl(__expf(log_alpha[0]));
  float Cc = 0.0f, dcoef[4] = {0, 0, 0, 0}, ecoef[6];
  PAIR(0,1) PAIR(0,2) PAIR(0,3) PAIR(0,4) PAIR(0,5) PAIR(0,6) PAIR(0,7) PAIR(0,8) PAIR(0,9)
  PAIR(1,2) PAIR(1,3) PAIR(1,4) PAIR(1,5) PAIR(1,6) PAIR(1,7) PAIR(1,8) PAIR(1,9)
  PAIR(2,3) PAIR(2,4) PAIR(2,5) PAIR(2,6) PAIR(2,7) PAIR(2,8) PAIR(2,9)
  PAIR(3,4) PAIR(3,5) PAIR(3,6) PAIR(3,7) PAIR(3,8) PAIR(3,9)
  PAIR(4,5) PAIR(4,6) PAIR(4,7) PAIR(4,8) PAIR(4,9)
  PAIR(5,6) PAIR(5,7) PAIR(5,8) PAIR(5,9)
  PAIR(6,7) PAIR(6,8) PAIR(6,9)
  PAIR(7,8) PAIR(7,9)
  PAIR(8,9)

  // ---- encoding angles: wave-uniform -> force into SGPRs ----
  float th[10], ph[10];
  #pragma unroll
  for (int q = 0; q < 10; ++q) {
    th[q] = rfl(c[1270 + q]);
    ph[q] = rfl(dcp[1270 + q]);
  }

  // ---- closed-form initial state: (prod_q RZ(ph)RY(th)|0>) * e^{i h} ----
  // single-qubit: RZ(ph)RY(th)|0> = (cos(th/2) e^{-i ph/2}, sin(th/2) e^{+i ph/2})
  // qubits 0..5 <-> lane bits 5..0 (product -> L, per lane)
  // qubits 6..9 <-> r bits 3..0    (product -> R[r], via uniform tables)
  float re[16], im[16];
  {
    float Lr = 1.0f, Li = 0.0f;
    #pragma unroll
    for (int q = 0; q < 6; ++q) {
      float cy, sy; __sincosf(0.5f * th[q], &sy, &cy);
      float cz, sz; __sincosf(0.5f * ph[q], &sz, &cz);
      const bool b = ((lane >> (5 - q)) & 1) != 0;
      const float zr = b ? sy * cz : cy * cz;
      const float zi = b ? sy * sz : -cy * sz;
      const float nr = Lr * zr - Li * zi;
      Li = Lr * zi + Li * zr;
      Lr = nr;
    }
    float ar[4][2], ai[4][2];
    #pragma unroll
    for (int t = 0; t < 4; ++t) {
      float cy, sy; __sincosf(0.5f * th[6 + t], &sy, &cy);
      float cz, sz; __sincosf(0.5f * ph[6 + t], &sz, &cz);
      ar[t][0] = rfl(cy * cz);  ai[t][0] = rfl(-cy * sz);
      ar[t][1] = rfl(sy * cz);  ai[t][1] = rfl( sy * sz);
    }
    #pragma unroll
    for (int r = 0; r < 16; ++r) {
      const int b3 = (r >> 3) & 1, b2 = (r >> 2) & 1, b1 = (r >> 1) & 1, b0 = r & 1;
      // R = a0[b3]*a1[b2]*a2[b1]*a3[b0]  (all uniform -> SGPR math folded)
      float Rr = ar[0][b3], Ri = ai[0][b3];
      float t1 = Rr * ar[1][b2] - Ri * ai[1][b2];
      Ri = Rr * ai[1][b2] + Ri * ar[1][b2]; Rr = t1;
      t1 = Rr * ar[2][b1] - Ri * ai[2][b1];
      Ri = Rr * ai[2][b1] + Ri * ar[2][b1]; Rr = t1;
      t1 = Rr * ar[3][b0] - Ri * ai[3][b0];
      Ri = Rr * ai[3][b0] + Ri * ar[3][b0]; Rr = t1;
      // ZZ phase angle
      float h = Cc;
      h += b3 ? -dcoef[0] : dcoef[0];
      h += b2 ? -dcoef[1] : dcoef[1];
      h += b1 ? -dcoef[2] : dcoef[2];
      h += b0 ? -dcoef[3] : dcoef[3];
      h += (b3 ^ b2) ? -ecoef[0] : ecoef[0];
      h += (b3 ^ b1) ? -ecoef[1] : ecoef[1];
      h += (b3 ^ b0) ? -ecoef[2] : ecoef[2];
      h += (b2 ^ b1) ? -ecoef[3] : ecoef[3];
      h += (b2 ^ b0) ? -ecoef[4] : ecoef[4];
      h += (b1 ^ b0) ? -ecoef[5] : ecoef[5];
      float sn, cs; __sincosf(h, &sn, &cs);
      // state = e^{ih} * L * R
      const float pr = cs * Lr - sn * Li;
      const float pi = cs * Li + sn * Lr;
      re[r] = pr * Rr - pi * Ri;
      im[r] = pr * Ri + pi * Rr;
    }
  }

  // ---- layer 0 ----
  ROT0(0) ROT0(1) ROT0(2) ROT0(3) ROT0(4) ROT0(5) ROT0(6) ROT0(7) ROT0(8) ROT0(9)
  CNOT(0,1) CNOT(1,1) CNOT(2,1) CNOT(3,1) CNOT(4,1)
  CNOT(5,1) CNOT(6,1) CNOT(7,1) CNOT(8,1) CNOT(9,1)
  // ---- re-encode(0.5) fused with layer-1 Rot ----
  MERGED(1,0) MERGED(1,1) MERGED(1,2) MERGED(1,3) MERGED(1,4)
  MERGED(1,5) MERGED(1,6) MERGED(1,7) MERGED(1,8) MERGED(1,9)
  CNOT(0,2) CNOT(1,2) CNOT(2,2) CNOT(3,2) CNOT(4,2)
  CNOT(5,2) CNOT(6,2) CNOT(7,2) CNOT(8,2) CNOT(9,2)
  // ---- re-encode(0.5) fused with layer-2 Rot ----
  MERGED(2,0) MERGED(2,1) MERGED(2,2) MERGED(2,3) MERGED(2,4)
  MERGED(2,5) MERGED(2,6) MERGED(2,7) MERGED(2,8) MERGED(2,9)
  CNOT(0,3) CNOT(1,3) CNOT(2,3) CNOT(3,3) CNOT(4,3)
  CNOT(5,3) CNOT(6,3) CNOT(7,3) CNOT(8,3) CNOT(9,3)

  // ---- measurement: Z expvals then 3-action projection ----
  float P = 0.0f, e6 = 0.0f, e7 = 0.0f, e8 = 0.0f, e9 = 0.0f;
  #pragma unroll
  for (int r = 0; r < 16; ++r) {
    const float pp = re[r]*re[r] + im[r]*im[r];
    P  += pp;
    e6 += (r & 8) ? -pp : pp;
    e7 += (r & 4) ? -pp : pp;
    e8 += (r & 2) ? -pp : pp;
    e9 += (r & 1) ? -pp : pp;
  }
  float ev[10];
  ev[0] = (lane & 32) ? -P : P;
  ev[1] = (lane & 16) ? -P : P;
  ev[2] = (lane &  8) ? -P : P;
  ev[3] = (lane &  4) ? -P : P;
  ev[4] = (lane &  2) ? -P : P;
  ev[5] = (lane &  1) ? -P : P;
  ev[6] = e6; ev[7] = e7; ev[8] = e8; ev[9] = e9;
  #pragma unroll
  for (int i = 0; i < 10; ++i) ev[i] = wred(ev[i]);

  if (lane < 3) {
    float acc = b_proj[lane];
    #pragma unroll
    for (int i = 0; i < 10; ++i) acc += w_proj[lane * 10 + i] * ev[i];
    out[(size_t)bid * 3 + lane] = acc;
  }
}

extern "C" void kernel_launch(void* const* d_in, const int* in_sizes, int n_in,
                              void* d_out, int out_size, void* d_ws, size_t ws_size,
                              hipStream_t stream) {
  (void)in_sizes; (void)n_in; (void)d_ws; (void)ws_size; (void)out_size;
  const float* c_kt      = (const float*)d_in[0];
  const float* dc_kt     = (const float*)d_in[1];
  const float* vw        = (const float*)d_in[2];
  const float* w_proj    = (const float*)d_in[3];
  const float* b_proj    = (const float*)d_in[4];
  const float* log_alpha = (const float*)d_in[5];
  float* out = (float*)d_out;
  // 4096 batch elems, 1 wave each, 4 waves per 256-thread block
  qhl_kernel<<<dim3(1024), dim3(256), 0, stream>>>(c_kt, dc_kt, vw, w_proj,
                                                   b_proj, log_alpha, out);
}

// Round 8
// 172.235 us; speedup vs baseline: 1.4316x; 1.1158x over previous
//
#include <hip/hip_runtime.h>

// One wave (64 lanes) per batch element. State: 1024 complex amps = 16/lane
// in registers (re[16], im[16]). s = lane*16 + r ; qubit q <-> s-bit (9-q).
// Bits 0..3 (qubits 6..9): in-register pairs. Bits 4..9 (qubits 0..5):
// cross-lane. No LDS, no __syncthreads.
//
// R1-R5: launch-bounds/VGPR-spill saga: fix was readfirstlane of all
//     wave-uniform gate coefficients into SGPRs (R6: 124us, spill ~0).
// R7: xor1/2/4/8 -> DPP (quad_perm / half_mirror∘quad / row_ror:8),
//     xor16 -> ds_swizzle 0x401F. BUG: xor32 via ds_swizzle 0x801F is
//     invalid (5-bit xor field; ds_swizzle never crosses 32 lanes) -> wrong
//     results (absmax 2.0).
// R8: xor32 via __shfl_xor(v,32) (ds_bpermute, full 64-lane crossbar).

// ---- cross-lane xor via DPP where possible ----
template<int CTRL>
__device__ __forceinline__ float dppf(float v) {
  return __int_as_float(__builtin_amdgcn_update_dpp(
      0, __float_as_int(v), CTRL, 0xF, 0xF, true));
}

template<int LM>
__device__ __forceinline__ float xshfl(float v) {
  if constexpr (LM == 1) {
    return dppf<0xB1>(v);               // quad_perm [1,0,3,2]
  } else if constexpr (LM == 2) {
    return dppf<0x4E>(v);               // quad_perm [2,3,0,1]
  } else if constexpr (LM == 4) {
    return dppf<0x141>(dppf<0x1B>(v));  // xor7(half_mirror) ∘ xor3(quad_perm)
  } else if constexpr (LM == 8) {
    return dppf<0x128>(v);              // row_ror:8 == xor8 within row16
  } else if constexpr (LM == 16) {
    return __int_as_float(__builtin_amdgcn_ds_swizzle(__float_as_int(v), 0x401F));
  } else {
    return __shfl_xor(v, 32);           // ds_bpermute crosses the 32-lane halves
  }
}

__device__ __forceinline__ float wred(float v) {
  v += xshfl<1>(v);
  v += xshfl<2>(v);
  v += xshfl<4>(v);
  v += xshfl<8>(v);
  v += xshfl<16>(v);
  v += xshfl<32>(v);
  return v;
}

// force a wave-uniform float into an SGPR
__device__ __forceinline__ float rfl(float x) {
  return __int_as_float(__builtin_amdgcn_readfirstlane(__float_as_int(x)));
}

// tanh(x) = 1 - 2/(exp(2x)+1); __expf saturates correctly at +-inf
__device__ __forceinline__ float fast_tanh(float x) {
  return 1.0f - 2.0f / (__expf(2.0f * x) + 1.0f);
}

template<int BIT>
__device__ __forceinline__ void gate_apply(float (&re)[16], float (&im)[16], int lane,
    float m00r, float m00i, float m01r, float m01i,
    float m10r, float m10i, float m11r, float m11i) {
  if constexpr (BIT < 4) {
    #pragma unroll
    for (int r0 = 0; r0 < 16; ++r0) {
      if ((r0 & (1 << BIT)) == 0) {
        const int r1 = r0 | (1 << BIT);
        const float a0r = re[r0], a0i = im[r0], a1r = re[r1], a1i = im[r1];
        re[r0] = m00r*a0r - m00i*a0i + m01r*a1r - m01i*a1i;
        im[r0] = m00r*a0i + m00i*a0r + m01r*a1i + m01i*a1r;
        re[r1] = m10r*a0r - m10i*a0i + m11r*a1r - m11i*a1i;
        im[r1] = m10r*a0i + m10i*a0r + m11r*a1i + m11i*a1r;
      }
    }
  } else {
    constexpr int lm = 1 << (BIT - 4);
    const bool hi = (lane & lm) != 0;
    // own-amp coeff / partner-amp coeff selected once per gate
    const float cAr = hi ? m11r : m00r, cAi = hi ? m11i : m00i;
    const float cBr = hi ? m10r : m01r, cBi = hi ? m10i : m01i;
    #pragma unroll
    for (int r = 0; r < 16; ++r) {
      const float pr = xshfl<lm>(re[r]);
      const float pi = xshfl<lm>(im[r]);
      const float ar = re[r], ai = im[r];
      re[r] = cAr*ar - cAi*ai + cBr*pr - cBi*pi;
      im[r] = cAr*ai + cAi*ar + cBr*pi + cBi*pr;
    }
  }
}

// new[s] = old[ s ^ (ctrlbit(s) ? tgtmask : 0) ]
template<int CB, int TB>
__device__ __forceinline__ void cnot_apply(float (&re)[16], float (&im)[16], int lane) {
  if constexpr (CB >= 4 && TB >= 4) {
    constexpr int lm = 1 << (TB - 4);
    const bool c1 = (lane & (1 << (CB - 4))) != 0;
    #pragma unroll
    for (int r = 0; r < 16; ++r) {
      const float pr = xshfl<lm>(re[r]);
      const float pi = xshfl<lm>(im[r]);
      re[r] = c1 ? pr : re[r];
      im[r] = c1 ? pi : im[r];
    }
  } else if constexpr (CB >= 4 && TB < 4) {
    const bool c1 = (lane & (1 << (CB - 4))) != 0;
    #pragma unroll
    for (int r0 = 0; r0 < 16; ++r0) {
      if ((r0 & (1 << TB)) == 0) {
        const int r1 = r0 | (1 << TB);
        const float ar = re[r0], br = re[r1];
        re[r0] = c1 ? br : ar;  re[r1] = c1 ? ar : br;
        const float ai = im[r0], bi = im[r1];
        im[r0] = c1 ? bi : ai;  im[r1] = c1 ? ai : bi;
      }
    }
  } else if constexpr (CB < 4 && TB >= 4) {
    constexpr int lm = 1 << (TB - 4);
    #pragma unroll
    for (int r = 0; r < 16; ++r) {
      if ((r & (1 << CB)) != 0) {     // compile-time per unrolled r
        re[r] = xshfl<lm>(re[r]);
        im[r] = xshfl<lm>(im[r]);
      }
    }
  } else {
    #pragma unroll
    for (int r0 = 0; r0 < 16; ++r0) {
      if ((r0 & (1 << CB)) != 0 && (r0 & (1 << TB)) == 0) {
        const int r1 = r0 | (1 << TB);
        float t = re[r0]; re[r0] = re[r1]; re[r1] = t;
        t = im[r0]; im[r0] = im[r1]; im[r1] = t;
      }
    }
  }
}

// half_ang(s) = 0.5*pi * sum_p J_p * mask_p(s),  mask = +1 iff bits differ = -z_i z_j
// decomposed: C(lane) [high-high] + d[j]*z_j(r) [high-low] + e[ij]*z_i(r)z_j(r) [low-low]
template<int I, int J>
__device__ __forceinline__ void pair_accum(float t, int lane, float& Cc,
                                           float (&dcf)[4], float (&ecf)[6]) {
  if constexpr (J <= 5) {
    const bool diff = (((lane >> (5 - I)) ^ (lane >> (5 - J))) & 1) != 0;
    Cc += diff ? -t : t;            // t * z_i(lane) * z_j(lane)
  } else if constexpr (I <= 5) {
    const bool b = ((lane >> (5 - I)) & 1) != 0;
    dcf[J - 6] += b ? -t : t;       // t * z_i(lane)
  } else {
    constexpr int eb = (I == 6) ? 0 : (I == 7) ? 3 : 5;
    ecf[eb + (J - I - 1)] = rfl(t); // wave-uniform -> SGPR
  }
}

#define PAIR(i, j) { \
  float dot_ = y0[i]*y0[j] + y1[i]*y1[j]; \
  dot_ = wred(dot_) * (1.0f/127.0f); \
  const float t_ = -1.5707963267948966f * fast_tanh(dot_ * expA); \
  pair_accum<i, j>(t_, lane, Cc, dcoef, ecoef); }

// layer-0 Rot: M = RZ(w2) RY(w1) RZ(w0). All coeffs wave-uniform -> SGPRs.
#define ROT0(q) { \
  const float w0 = vw[(q)*3+0], w1 = vw[(q)*3+1], w2 = vw[(q)*3+2]; \
  float cy, sy; __sincosf(0.5f*w1, &sy, &cy); \
  float ca, sa; __sincosf(0.5f*(w0+w2), &sa, &ca); \
  float cb, sb; __sincosf(0.5f*(w0-w2), &sb, &cb); \
  gate_apply<9 - (q)>(re, im, lane, \
      rfl(cy*ca), rfl(-cy*sa),  rfl(-sy*cb), rfl(-sy*sb), \
      rfl(sy*cb), rfl(-sy*sb),  rfl( cy*ca), rfl( cy*sa)); }

// fused: EncHalf (RZ(phi/2)RY(theta/2)) followed by layer-l Rot  ->  M = R * E
// All 8 matrix elements wave-uniform -> SGPRs.
#define MERGED(l, q) { \
  float cy, sy; __sincosf(0.25f * th[q], &sy, &cy); \
  float cz, sz; __sincosf(0.25f * ph[q], &sz, &cz); \
  const float e00r =  cy*cz, e00i = -cy*sz, e01r = -sy*cz, e01i =  sy*sz; \
  const float e10r =  sy*cz, e10i =  sy*sz, e11r =  cy*cz, e11i =  cy*sz; \
  const float w0 = vw[((l)*10+(q))*3+0], w1 = vw[((l)*10+(q))*3+1], w2 = vw[((l)*10+(q))*3+2]; \
  float cY, sY; __sincosf(0.5f*w1, &sY, &cY); \
  float ca, sa; __sincosf(0.5f*(w0+w2), &sa, &ca); \
  float cb, sb; __sincosf(0.5f*(w0-w2), &sb, &cb); \
  const float r00r =  cY*ca, r00i = -cY*sa, r01r = -sY*cb, r01i = -sY*sb; \
  const float r10r =  sY*cb, r10i = -sY*sb, r11r =  cY*ca, r11i =  cY*sa; \
  gate_apply<9 - (q)>(re, im, lane, \
      rfl(r00r*e00r - r00i*e00i + r01r*e10r - r01i*e10i), \
      rfl(r00r*e00i + r00i*e00r + r01r*e10i + r01i*e10r), \
      rfl(r00r*e01r - r00i*e01i + r01r*e11r - r01i*e11i), \
      rfl(r00r*e01i + r00i*e01r + r01r*e11i + r01i*e11r), \
      rfl(r10r*e00r - r10i*e00i + r11r*e10r - r11i*e10i), \
      rfl(r10r*e00i + r10i*e00r + r11r*e10i + r11i*e10r), \
      rfl(r10r*e01r - r10i*e01i + r11r*e11r - r11i*e11i), \
      rfl(r10r*e01i + r10i*e01r + r11r*e11i + r11i*e11r)); }

#define CNOT(ctrl, rng) cnot_apply<9 - (ctrl), 9 - ((((ctrl) + (rng)) % 10))>(re, im, lane);

extern "C" __global__ void __launch_bounds__(256, 2)
qhl_kernel(const float* __restrict__ c_kt, const float* __restrict__ dc_kt,
           const float* __restrict__ vw,  const float* __restrict__ w_proj,
           const float* __restrict__ b_proj, const float* __restrict__ log_alpha,
           float* __restrict__ out) {
  const int wave = threadIdx.x >> 6;
  const int lane = threadIdx.x & 63;
  const int bid  = blockIdx.x * 4 + wave;

  const float* c   = c_kt  + (size_t)bid * 1280;
  const float* dcp = dc_kt + (size_t)bid * 1280;

  // ---- correlation: rows held in registers, stats via wave reductions ----
  // row stride 10 floats = 40B = 8B-aligned -> float2 loads (5 per row)
  float y0[10], y1[10];
  {
    const float2* c0 = (const float2*)(c   + lane * 10);
    const float2* d0 = (const float2*)(dcp + lane * 10);
    const float2* c1 = (const float2*)(c   + (lane + 64) * 10);
    const float2* d1 = (const float2*)(dcp + (lane + 64) * 10);
    #pragma unroll
    for (int k = 0; k < 5; ++k) {
      const float2 a0 = c0[k], b0 = d0[k], a1 = c1[k], b1 = d1[k];
      y0[2*k]   = a0.x + 0.5f * b0.x;  y0[2*k+1] = a0.y + 0.5f * b0.y;
      y1[2*k]   = a1.x + 0.5f * b1.x;  y1[2*k+1] = a1.y + 0.5f * b1.y;
    }
  }
  #pragma unroll
  for (int k = 0; k < 10; ++k) {
    const float mean = wred(y0[k] + y1[k]) * (1.0f / 128.0f);
    y0[k] -= mean; y1[k] -= mean;
    const float ss = wred(y0[k]*y0[k] + y1[k]*y1[k]);
    // rs = 1 / max(sqrt(ss/127), 1e-8)
    const float rs = fminf(__builtin_amdgcn_rsqf(ss * (1.0f / 127.0f)), 1e8f);
    y0[k] *= rs; y1[k] *= rs;
  }

  const float expA = rfl(__expf(log_alpha[0]));
  float Cc = 0.0f, dcoef[4] = {0, 0, 0, 0}, ecoef[6];
  PAIR(0,1) PAIR(0,2) PAIR(0,3) PAIR(0,4) PAIR(0,5) PAIR(0,6) PAIR(0,7) PAIR(0,8) PAIR(0,9)
  PAIR(1,2) PAIR(1,3) PAIR(1,4) PAIR(1,5) PAIR(1,6) PAIR(1,7) PAIR(1,8) PAIR(1,9)
  PAIR(2,3) PAIR(2,4) PAIR(2,5) PAIR(2,6) PAIR(2,7) PAIR(2,8) PAIR(2,9)
  PAIR(3,4) PAIR(3,5) PAIR(3,6) PAIR(3,7) PAIR(3,8) PAIR(3,9)
  PAIR(4,5) PAIR(4,6) PAIR(4,7) PAIR(4,8) PAIR(4,9)
  PAIR(5,6) PAIR(5,7) PAIR(5,8) PAIR(5,9)
  PAIR(6,7) PAIR(6,8) PAIR(6,9)
  PAIR(7,8) PAIR(7,9)
  PAIR(8,9)

  // ---- encoding angles: wave-uniform -> force into SGPRs ----
  float th[10], ph[10];
  #pragma unroll
  for (int q = 0; q < 10; ++q) {
    th[q] = rfl(c[1270 + q]);
    ph[q] = rfl(dcp[1270 + q]);
  }

  // ---- closed-form initial state: (prod_q RZ(ph)RY(th)|0>) * e^{i h} ----
  // single-qubit: RZ(ph)RY(th)|0> = (cos(th/2) e^{-i ph/2}, sin(th/2) e^{+i ph/2})
  // qubits 0..5 <-> lane bits 5..0 (product -> L, per lane)
  // qubits 6..9 <-> r bits 3..0    (product -> R[r], via uniform tables)
  float re[16], im[16];
  {
    float Lr = 1.0f, Li = 0.0f;
    #pragma unroll
    for (int q = 0; q < 6; ++q) {
      float cy, sy; __sincosf(0.5f * th[q], &sy, &cy);
      float cz, sz; __sincosf(0.5f * ph[q], &sz, &cz);
      const bool b = ((lane >> (5 - q)) & 1) != 0;
      const float zr = b ? sy * cz : cy * cz;
      const float zi = b ? sy * sz : -cy * sz;
      const float nr = Lr * zr - Li * zi;
      Li = Lr * zi + Li * zr;
      Lr = nr;
    }
    float ar[4][2], ai[4][2];
    #pragma unroll
    for (int t = 0; t < 4; ++t) {
      float cy, sy; __sincosf(0.5f * th[6 + t], &sy, &cy);
      float cz, sz; __sincosf(0.5f * ph[6 + t], &sz, &cz);
      ar[t][0] = rfl(cy * cz);  ai[t][0] = rfl(-cy * sz);
      ar[t][1] = rfl(sy * cz);  ai[t][1] = rfl( sy * sz);
    }
    #pragma unroll
    for (int r = 0; r < 16; ++r) {
      const int b3 = (r >> 3) & 1, b2 = (r >> 2) & 1, b1 = (r >> 1) & 1, b0 = r & 1;
      // R = a0[b3]*a1[b2]*a2[b1]*a3[b0]  (all uniform -> SGPR math folded)
      float Rr = ar[0][b3], Ri = ai[0][b3];
      float t1 = Rr * ar[1][b2] - Ri * ai[1][b2];
      Ri = Rr * ai[1][b2] + Ri * ar[1][b2]; Rr = t1;
      t1 = Rr * ar[2][b1] - Ri * ai[2][b1];
      Ri = Rr * ai[2][b1] + Ri * ar[2][b1]; Rr = t1;
      t1 = Rr * ar[3][b0] - Ri * ai[3][b0];
      Ri = Rr * ai[3][b0] + Ri * ar[3][b0]; Rr = t1;
      // ZZ phase angle
      float h = Cc;
      h += b3 ? -dcoef[0] : dcoef[0];
      h += b2 ? -dcoef[1] : dcoef[1];
      h += b1 ? -dcoef[2] : dcoef[2];
      h += b0 ? -dcoef[3] : dcoef[3];
      h += (b3 ^ b2) ? -ecoef[0] : ecoef[0];
      h += (b3 ^ b1) ? -ecoef[1] : ecoef[1];
      h += (b3 ^ b0) ? -ecoef[2] : ecoef[2];
      h += (b2 ^ b1) ? -ecoef[3] : ecoef[3];
      h += (b2 ^ b0) ? -ecoef[4] : ecoef[4];
      h += (b1 ^ b0) ? -ecoef[5] : ecoef[5];
      float sn, cs; __sincosf(h, &sn, &cs);
      // state = e^{ih} * L * R
      const float pr = cs * Lr - sn * Li;
      const float pi = cs * Li + sn * Lr;
      re[r] = pr * Rr - pi * Ri;
      im[r] = pr * Ri + pi * Rr;
    }
  }

  // ---- layer 0 ----
  ROT0(0) ROT0(1) ROT0(2) ROT0(3) ROT0(4) ROT0(5) ROT0(6) ROT0(7) ROT0(8) ROT0(9)
  CNOT(0,1) CNOT(1,1) CNOT(2,1) CNOT(3,1) CNOT(4,1)
  CNOT(5,1) CNOT(6,1) CNOT(7,1) CNOT(8,1) CNOT(9,1)
  // ---- re-encode(0.5) fused with layer-1 Rot ----
  MERGED(1,0) MERGED(1,1) MERGED(1,2) MERGED(1,3) MERGED(1,4)
  MERGED(1,5) MERGED(1,6) MERGED(1,7) MERGED(1,8) MERGED(1,9)
  CNOT(0,2) CNOT(1,2) CNOT(2,2) CNOT(3,2) CNOT(4,2)
  CNOT(5,2) CNOT(6,2) CNOT(7,2) CNOT(8,2) CNOT(9,2)
  // ---- re-encode(0.5) fused with layer-2 Rot ----
  MERGED(2,0) MERGED(2,1) MERGED(2,2) MERGED(2,3) MERGED(2,4)
  MERGED(2,5) MERGED(2,6) MERGED(2,7) MERGED(2,8) MERGED(2,9)
  CNOT(0,3) CNOT(1,3) CNOT(2,3) CNOT(3,3) CNOT(4,3)
  CNOT(5,3) CNOT(6,3) CNOT(7,3) CNOT(8,3) CNOT(9,3)

  // ---- measurement: Z expvals then 3-action projection ----
  float P = 0.0f, e6 = 0.0f, e7 = 0.0f, e8 = 0.0f, e9 = 0.0f;
  #pragma unroll
  for (int r = 0; r < 16; ++r) {
    const float pp = re[r]*re[r] + im[r]*im[r];
    P  += pp;
    e6 += (r & 8) ? -pp : pp;
    e7 += (r & 4) ? -pp : pp;
    e8 += (r & 2) ? -pp : pp;
    e9 += (r & 1) ? -pp : pp;
  }
  float ev[10];
  ev[0] = (lane & 32) ? -P : P;
  ev[1] = (lane & 16) ? -P : P;
  ev[2] = (lane &  8) ? -P : P;
  ev[3] = (lane &  4) ? -P : P;
  ev[4] = (lane &  2) ? -P : P;
  ev[5] = (lane &  1) ? -P : P;
  ev[6] = e6; ev[7] = e7; ev[8] = e8; ev[9] = e9;
  #pragma unroll
  for (int i = 0; i < 10; ++i) ev[i] = wred(ev[i]);

  if (lane < 3) {
    float acc = b_proj[lane];
    #pragma unroll
    for (int i = 0; i < 10; ++i) acc += w_proj[lane * 10 + i] * ev[i];
    out[(size_t)bid * 3 + lane] = acc;
  }
}

extern "C" void kernel_launch(void* const* d_in, const int* in_sizes, int n_in,
                              void* d_out, int out_size, void* d_ws, size_t ws_size,
                              hipStream_t stream) {
  (void)in_sizes; (void)n_in; (void)d_ws; (void)ws_size; (void)out_size;
  const float* c_kt      = (const float*)d_in[0];
  const float* dc_kt     = (const float*)d_in[1];
  const float* vw        = (const float*)d_in[2];
  const float* w_proj    = (const float*)d_in[3];
  const float* b_proj    = (const float*)d_in[4];
  const float* log_alpha = (const float*)d_in[5];
  float* out = (float*)d_out;
  // 4096 batch elems, 1 wave each, 4 waves per 256-thread block
  qhl_kernel<<<dim3(1024), dim3(256), 0, stream>>>(c_kt, dc_kt, vw, w_proj,
                                                   b_proj, log_alpha, out);
}

// Round 9
// 160.108 us; speedup vs baseline: 1.5400x; 1.0757x over previous
//
#include <hip/hip_runtime.h>

// One wave (64 lanes) per batch element. State: 1024 complex amps = 16/lane
// held as PACKED float2 (re,im) registers -> v_pk_fma_f32 (2x fp32 issue
// rate; this is how gfx950 reaches its 157TF fp32 peak).
// s = lane*16 + r ; qubit q <-> s-bit (9-q). Bits 0..3: in-register pairs.
// Bits 4..9: cross-lane via DPP (xor1/2/4/8), ds_swizzle(xor16),
// shfl_xor(xor32). No LDS, no __syncthreads.
//
// R1-R5: VGPR-spill saga -> fix: readfirstlane all wave-uniform gate coeffs
//     into SGPRs (R6: 124us). R7: DPP for xor1/2/4/8 (BUG: ds_swizzle can't
//     cross 32 lanes). R8: xor32 via __shfl_xor -> 105us, VALUBusy 77%.
// R9: VALU-issue-bound -> pack (re,im) as float2, complex MAC = cr*a +
//     ci*sneg(a) -> pk_fma, ~halving gate FMA slots. Corr rows packed too.

typedef float v2 __attribute__((ext_vector_type(2)));

// ---- cross-lane xor via DPP where possible ----
template<int CTRL>
__device__ __forceinline__ float dppf(float v) {
  return __int_as_float(__builtin_amdgcn_update_dpp(
      0, __float_as_int(v), CTRL, 0xF, 0xF, true));
}

template<int LM>
__device__ __forceinline__ float xshfl(float v) {
  if constexpr (LM == 1) {
    return dppf<0xB1>(v);               // quad_perm [1,0,3,2]
  } else if constexpr (LM == 2) {
    return dppf<0x4E>(v);               // quad_perm [2,3,0,1]
  } else if constexpr (LM == 4) {
    return dppf<0x141>(dppf<0x1B>(v));  // xor7(half_mirror) ∘ xor3(quad_perm)
  } else if constexpr (LM == 8) {
    return dppf<0x128>(v);              // row_ror:8 == xor8 within row16
  } else if constexpr (LM == 16) {
    return __int_as_float(__builtin_amdgcn_ds_swizzle(__float_as_int(v), 0x401F));
  } else {
    return __shfl_xor(v, 32);           // ds_bpermute crosses the 32-lane halves
  }
}

template<int LM>
__device__ __forceinline__ v2 xshfl2(v2 v) {
  v2 r; r.x = xshfl<LM>(v.x); r.y = xshfl<LM>(v.y); return r;
}

__device__ __forceinline__ float wred(float v) {
  v += xshfl<1>(v);
  v += xshfl<2>(v);
  v += xshfl<4>(v);
  v += xshfl<8>(v);
  v += xshfl<16>(v);
  v += xshfl<32>(v);
  return v;
}

// force a wave-uniform float into an SGPR
__device__ __forceinline__ float rfl(float x) {
  return __int_as_float(__builtin_amdgcn_readfirstlane(__float_as_int(x)));
}

// tanh(x) = 1 - 2/(exp(2x)+1); __expf saturates correctly at +-inf
__device__ __forceinline__ float fast_tanh(float x) {
  return 1.0f - 2.0f / (__expf(2.0f * x) + 1.0f);
}

// i * a  as packed pair: (re,im) -> (-im, re)
__device__ __forceinline__ v2 sneg(v2 a) {
  v2 r; r.x = -a.y; r.y = a.x; return r;
}

template<int BIT>
__device__ __forceinline__ void gate_apply(v2 (&st)[16], int lane,
    float m00r, float m00i, float m01r, float m01i,
    float m10r, float m10i, float m11r, float m11i) {
  if constexpr (BIT < 4) {
    #pragma unroll
    for (int r0 = 0; r0 < 16; ++r0) {
      if ((r0 & (1 << BIT)) == 0) {
        const int r1 = r0 | (1 << BIT);
        const v2 a0 = st[r0], a1 = st[r1];
        const v2 s0 = sneg(a0), s1 = sneg(a1);
        st[r0] = m00r*a0 + m00i*s0 + m01r*a1 + m01i*s1;
        st[r1] = m10r*a0 + m10i*s0 + m11r*a1 + m11i*s1;
      }
    }
  } else {
    constexpr int lm = 1 << (BIT - 4);
    const bool hi = (lane & lm) != 0;
    // own-amp coeff / partner-amp coeff selected once per gate
    const float cAr = hi ? m11r : m00r, cAi = hi ? m11i : m00i;
    const float cBr = hi ? m10r : m01r, cBi = hi ? m10i : m01i;
    #pragma unroll
    for (int r = 0; r < 16; ++r) {
      const v2 p = xshfl2<lm>(st[r]);
      const v2 a = st[r];
      st[r] = cAr*a + cAi*sneg(a) + cBr*p + cBi*sneg(p);
    }
  }
}

// new[s] = old[ s ^ (ctrlbit(s) ? tgtmask : 0) ]
template<int CB, int TB>
__device__ __forceinline__ void cnot_apply(v2 (&st)[16], int lane) {
  if constexpr (CB >= 4 && TB >= 4) {
    constexpr int lm = 1 << (TB - 4);
    const bool c1 = (lane & (1 << (CB - 4))) != 0;
    #pragma unroll
    for (int r = 0; r < 16; ++r) {
      const v2 p = xshfl2<lm>(st[r]);
      st[r].x = c1 ? p.x : st[r].x;
      st[r].y = c1 ? p.y : st[r].y;
    }
  } else if constexpr (CB >= 4 && TB < 4) {
    const bool c1 = (lane & (1 << (CB - 4))) != 0;
    #pragma unroll
    for (int r0 = 0; r0 < 16; ++r0) {
      if ((r0 & (1 << TB)) == 0) {
        const int r1 = r0 | (1 << TB);
        const v2 a = st[r0], b = st[r1];
        st[r0].x = c1 ? b.x : a.x;  st[r0].y = c1 ? b.y : a.y;
        st[r1].x = c1 ? a.x : b.x;  st[r1].y = c1 ? a.y : b.y;
      }
    }
  } else if constexpr (CB < 4 && TB >= 4) {
    constexpr int lm = 1 << (TB - 4);
    #pragma unroll
    for (int r = 0; r < 16; ++r) {
      if ((r & (1 << CB)) != 0) {     // compile-time per unrolled r
        st[r] = xshfl2<lm>(st[r]);
      }
    }
  } else {
    #pragma unroll
    for (int r0 = 0; r0 < 16; ++r0) {
      if ((r0 & (1 << CB)) != 0 && (r0 & (1 << TB)) == 0) {
        const int r1 = r0 | (1 << TB);
        const v2 t = st[r0]; st[r0] = st[r1]; st[r1] = t;
      }
    }
  }
}

// half_ang(s) = 0.5*pi * sum_p J_p * mask_p(s),  mask = +1 iff bits differ = -z_i z_j
// decomposed: C(lane) [high-high] + d[j]*z_j(r) [high-low] + e[ij]*z_i(r)z_j(r) [low-low]
template<int I, int J>
__device__ __forceinline__ void pair_accum(float t, int lane, float& Cc,
                                           float (&dcf)[4], float (&ecf)[6]) {
  if constexpr (J <= 5) {
    const bool diff = (((lane >> (5 - I)) ^ (lane >> (5 - J))) & 1) != 0;
    Cc += diff ? -t : t;            // t * z_i(lane) * z_j(lane)
  } else if constexpr (I <= 5) {
    const bool b = ((lane >> (5 - I)) & 1) != 0;
    dcf[J - 6] += b ? -t : t;       // t * z_i(lane)
  } else {
    constexpr int eb = (I == 6) ? 0 : (I == 7) ? 3 : 5;
    ecf[eb + (J - I - 1)] = rfl(t); // wave-uniform -> SGPR
  }
}

#define PAIR(i, j) { \
  const v2 pr_ = ym[i] * ym[j]; \
  float dot_ = wred(pr_.x + pr_.y) * (1.0f/127.0f); \
  const float t_ = -1.5707963267948966f * fast_tanh(dot_ * expA); \
  pair_accum<i, j>(t_, lane, Cc, dcoef, ecoef); }

// layer-0 Rot: M = RZ(w2) RY(w1) RZ(w0). All coeffs wave-uniform -> SGPRs.
#define ROT0(q) { \
  const float w0 = vw[(q)*3+0], w1 = vw[(q)*3+1], w2 = vw[(q)*3+2]; \
  float cy, sy; __sincosf(0.5f*w1, &sy, &cy); \
  float ca, sa; __sincosf(0.5f*(w0+w2), &sa, &ca); \
  float cb, sb; __sincosf(0.5f*(w0-w2), &sb, &cb); \
  gate_apply<9 - (q)>(st, lane, \
      rfl(cy*ca), rfl(-cy*sa),  rfl(-sy*cb), rfl(-sy*sb), \
      rfl(sy*cb), rfl(-sy*sb),  rfl( cy*ca), rfl( cy*sa)); }

// fused: EncHalf (RZ(phi/2)RY(theta/2)) followed by layer-l Rot  ->  M = R * E
// All 8 matrix elements wave-uniform -> SGPRs.
#define MERGED(l, q) { \
  float cy, sy; __sincosf(0.25f * th[q], &sy, &cy); \
  float cz, sz; __sincosf(0.25f * ph[q], &sz, &cz); \
  const float e00r =  cy*cz, e00i = -cy*sz, e01r = -sy*cz, e01i =  sy*sz; \
  const float e10r =  sy*cz, e10i =  sy*sz, e11r =  cy*cz, e11i =  cy*sz; \
  const float w0 = vw[((l)*10+(q))*3+0], w1 = vw[((l)*10+(q))*3+1], w2 = vw[((l)*10+(q))*3+2]; \
  float cY, sY; __sincosf(0.5f*w1, &sY, &cY); \
  float ca, sa; __sincosf(0.5f*(w0+w2), &sa, &ca); \
  float cb, sb; __sincosf(0.5f*(w0-w2), &sb, &cb); \
  const float r00r =  cY*ca, r00i = -cY*sa, r01r = -sY*cb, r01i = -sY*sb; \
  const float r10r =  sY*cb, r10i = -sY*sb, r11r =  cY*ca, r11i =  cY*sa; \
  gate_apply<9 - (q)>(st, lane, \
      rfl(r00r*e00r - r00i*e00i + r01r*e10r - r01i*e10i), \
      rfl(r00r*e00i + r00i*e00r + r01r*e10i + r01i*e10r), \
      rfl(r00r*e01r - r00i*e01i + r01r*e11r - r01i*e11i), \
      rfl(r00r*e01i + r00i*e01r + r01r*e11i + r01i*e11r), \
      rfl(r10r*e00r - r10i*e00i + r11r*e10r - r11i*e10i), \
      rfl(r10r*e00i + r10i*e00r + r11r*e10i + r11i*e10r), \
      rfl(r10r*e01r - r10i*e01i + r11r*e11r - r11i*e11i), \
      rfl(r10r*e01i + r10i*e01r + r11r*e11i + r11i*e11r)); }

#define CNOT(ctrl, rng) cnot_apply<9 - (ctrl), 9 - ((((ctrl) + (rng)) % 10))>(st, lane);

extern "C" __global__ void __launch_bounds__(256, 2)
qhl_kernel(const float* __restrict__ c_kt, const float* __restrict__ dc_kt,
           const float* __restrict__ vw,  const float* __restrict__ w_proj,
           const float* __restrict__ b_proj, const float* __restrict__ log_alpha,
           float* __restrict__ out) {
  const int wave = threadIdx.x >> 6;
  const int lane = threadIdx.x & 63;
  const int bid  = blockIdx.x * 4 + wave;

  const float* c   = c_kt  + (size_t)bid * 1280;
  const float* dcp = dc_kt + (size_t)bid * 1280;

  // ---- correlation: rows packed as (row_lane, row_lane+64) float2 pairs ----
  v2 ym[10];
  {
    const float2* c0 = (const float2*)(c   + lane * 10);
    const float2* d0 = (const float2*)(dcp + lane * 10);
    const float2* c1 = (const float2*)(c   + (lane + 64) * 10);
    const float2* d1 = (const float2*)(dcp + (lane + 64) * 10);
    #pragma unroll
    for (int k = 0; k < 5; ++k) {
      const float2 a0 = c0[k], b0 = d0[k], a1 = c1[k], b1 = d1[k];
      ym[2*k].x   = a0.x + 0.5f * b0.x;  ym[2*k].y   = a1.x + 0.5f * b1.x;
      ym[2*k+1].x = a0.y + 0.5f * b0.y;  ym[2*k+1].y = a1.y + 0.5f * b1.y;
    }
  }
  #pragma unroll
  for (int k = 0; k < 10; ++k) {
    const float mean = wred(ym[k].x + ym[k].y) * (1.0f / 128.0f);
    ym[k].x -= mean; ym[k].y -= mean;
    const v2 sq = ym[k] * ym[k];
    const float ss = wred(sq.x + sq.y);
    // rs = 1 / max(sqrt(ss/127), 1e-8)
    const float rs = fminf(__builtin_amdgcn_rsqf(ss * (1.0f / 127.0f)), 1e8f);
    ym[k] *= rs;
  }

  const float expA = rfl(__expf(log_alpha[0]));
  float Cc = 0.0f, dcoef[4] = {0, 0, 0, 0}, ecoef[6];
  PAIR(0,1) PAIR(0,2) PAIR(0,3) PAIR(0,4) PAIR(0,5) PAIR(0,6) PAIR(0,7) PAIR(0,8) PAIR(0,9)
  PAIR(1,2) PAIR(1,3) PAIR(1,4) PAIR(1,5) PAIR(1,6) PAIR(1,7) PAIR(1,8) PAIR(1,9)
  PAIR(2,3) PAIR(2,4) PAIR(2,5) PAIR(2,6) PAIR(2,7) PAIR(2,8) PAIR(2,9)
  PAIR(3,4) PAIR(3,5) PAIR(3,6) PAIR(3,7) PAIR(3,8) PAIR(3,9)
  PAIR(4,5) PAIR(4,6) PAIR(4,7) PAIR(4,8) PAIR(4,9)
  PAIR(5,6) PAIR(5,7) PAIR(5,8) PAIR(5,9)
  PAIR(6,7) PAIR(6,8) PAIR(6,9)
  PAIR(7,8) PAIR(7,9)
  PAIR(8,9)

  // ---- encoding angles: wave-uniform -> force into SGPRs ----
  float th[10], ph[10];
  #pragma unroll
  for (int q = 0; q < 10; ++q) {
    th[q] = rfl(c[1270 + q]);
    ph[q] = rfl(dcp[1270 + q]);
  }

  // ---- closed-form initial state: (prod_q RZ(ph)RY(th)|0>) * e^{i h} ----
  // single-qubit: RZ(ph)RY(th)|0> = (cos(th/2) e^{-i ph/2}, sin(th/2) e^{+i ph/2})
  // qubits 0..5 <-> lane bits 5..0 (product -> L, per lane)
  // qubits 6..9 <-> r bits 3..0    (product -> R[r], via uniform tables)
  v2 st[16];
  {
    v2 L; L.x = 1.0f; L.y = 0.0f;
    #pragma unroll
    for (int q = 0; q < 6; ++q) {
      float cy, sy; __sincosf(0.5f * th[q], &sy, &cy);
      float cz, sz; __sincosf(0.5f * ph[q], &sz, &cz);
      const bool b = ((lane >> (5 - q)) & 1) != 0;
      const float zr = b ? sy * cz : cy * cz;
      const float zi = b ? sy * sz : -cy * sz;
      L = zr * L + zi * sneg(L);
    }
    float ar[4][2], ai[4][2];
    #pragma unroll
    for (int t = 0; t < 4; ++t) {
      float cy, sy; __sincosf(0.5f * th[6 + t], &sy, &cy);
      float cz, sz; __sincosf(0.5f * ph[6 + t], &sz, &cz);
      ar[t][0] = rfl(cy * cz);  ai[t][0] = rfl(-cy * sz);
      ar[t][1] = rfl(sy * cz);  ai[t][1] = rfl( sy * sz);
    }
    #pragma unroll
    for (int r = 0; r < 16; ++r) {
      const int b3 = (r >> 3) & 1, b2 = (r >> 2) & 1, b1 = (r >> 1) & 1, b0 = r & 1;
      // R = a0[b3]*a1[b2]*a2[b1]*a3[b0]  (all uniform -> SGPR math folded)
      float Rr = ar[0][b3], Ri = ai[0][b3];
      float t1 = Rr * ar[1][b2] - Ri * ai[1][b2];
      Ri = Rr * ai[1][b2] + Ri * ar[1][b2]; Rr = t1;
      t1 = Rr * ar[2][b1] - Ri * ai[2][b1];
      Ri = Rr * ai[2][b1] + Ri * ar[2][b1]; Rr = t1;
      t1 = Rr * ar[3][b0] - Ri * ai[3][b0];
      Ri = Rr * ai[3][b0] + Ri * ar[3][b0]; Rr = t1;
      // ZZ phase angle
      float h = Cc;
      h += b3 ? -dcoef[0] : dcoef[0];
      h += b2 ? -dcoef[1] : dcoef[1];
      h += b1 ? -dcoef[2] : dcoef[2];
      h += b0 ? -dcoef[3] : dcoef[3];
      h += (b3 ^ b2) ? -ecoef[0] : ecoef[0];
      h += (b3 ^ b1) ? -ecoef[1] : ecoef[1];
      h += (b3 ^ b0) ? -ecoef[2] : ecoef[2];
      h += (b2 ^ b1) ? -ecoef[3] : ecoef[3];
      h += (b2 ^ b0) ? -ecoef[4] : ecoef[4];
      h += (b1 ^ b0) ? -ecoef[5] : ecoef[5];
      float sn, cs; __sincosf(h, &sn, &cs);
      // st = (e^{ih} * L) * R
      const v2 p = cs * L + sn * sneg(L);
      st[r] = Rr * p + Ri * sneg(p);
    }
  }

  // ---- layer 0 ----
  ROT0(0) ROT0(1) ROT0(2) ROT0(3) ROT0(4) ROT0(5) ROT0(6) ROT0(7) ROT0(8) ROT0(9)
  CNOT(0,1) CNOT(1,1) CNOT(2,1) CNOT(3,1) CNOT(4,1)
  CNOT(5,1) CNOT(6,1) CNOT(7,1) CNOT(8,1) CNOT(9,1)
  // ---- re-encode(0.5) fused with layer-1 Rot ----
  MERGED(1,0) MERGED(1,1) MERGED(1,2) MERGED(1,3) MERGED(1,4)
  MERGED(1,5) MERGED(1,6) MERGED(1,7) MERGED(1,8) MERGED(1,9)
  CNOT(0,2) CNOT(1,2) CNOT(2,2) CNOT(3,2) CNOT(4,2)
  CNOT(5,2) CNOT(6,2) CNOT(7,2) CNOT(8,2) CNOT(9,2)
  // ---- re-encode(0.5) fused with layer-2 Rot ----
  MERGED(2,0) MERGED(2,1) MERGED(2,2) MERGED(2,3) MERGED(2,4)
  MERGED(2,5) MERGED(2,6) MERGED(2,7) MERGED(2,8) MERGED(2,9)
  CNOT(0,3) CNOT(1,3) CNOT(2,3) CNOT(3,3) CNOT(4,3)
  CNOT(5,3) CNOT(6,3) CNOT(7,3) CNOT(8,3) CNOT(9,3)

  // ---- measurement: Z expvals then 3-action projection ----
  float P = 0.0f, e6 = 0.0f, e7 = 0.0f, e8 = 0.0f, e9 = 0.0f;
  #pragma unroll
  for (int r = 0; r < 16; ++r) {
    const v2 sq = st[r] * st[r];
    const float pp = sq.x + sq.y;
    P  += pp;
    e6 += (r & 8) ? -pp : pp;
    e7 += (r & 4) ? -pp : pp;
    e8 += (r & 2) ? -pp : pp;
    e9 += (r & 1) ? -pp : pp;
  }
  float ev[10];
  ev[0] = (lane & 32) ? -P : P;
  ev[1] = (lane & 16) ? -P : P;
  ev[2] = (lane &  8) ? -P : P;
  ev[3] = (lane &  4) ? -P : P;
  ev[4] = (lane &  2) ? -P : P;
  ev[5] = (lane &  1) ? -P : P;
  ev[6] = e6; ev[7] = e7; ev[8] = e8; ev[9] = e9;
  #pragma unroll
  for (int i = 0; i < 10; ++i) ev[i] = wred(ev[i]);

  if (lane < 3) {
    float acc = b_proj[lane];
    #pragma unroll
    for (int i = 0; i < 10; ++i) acc += w_proj[lane * 10 + i] * ev[i];
    out[(size_t)bid * 3 + lane] = acc;
  }
}

extern "C" void kernel_launch(void* const* d_in, const int* in_sizes, int n_in,
                              void* d_out, int out_size, void* d_ws, size_t ws_size,
                              hipStream_t stream) {
  (void)in_sizes; (void)n_in; (void)d_ws; (void)ws_size; (void)out_size;
  const float* c_kt      = (const float*)d_in[0];
  const float* dc_kt     = (const float*)d_in[1];
  const float* vw        = (const float*)d_in[2];
  const float* w_proj    = (const float*)d_in[3];
  const float* b_proj    = (const float*)d_in[4];
  const float* log_alpha = (const float*)d_in[5];
  float* out = (float*)d_out;
  // 4096 batch elems, 1 wave each, 4 waves per 256-thread block
  qhl_kernel<<<dim3(1024), dim3(256), 0, stream>>>(c_kt, dc_kt, vw, w_proj,
                                                   b_proj, log_alpha, out);
}

// Round 10
// 142.464 us; speedup vs baseline: 1.7307x; 1.1238x over previous
//
#include <hip/hip_runtime.h>

// One wave (64 lanes) per batch element. State: 1024 complex amps = 16/lane
// held as PACKED float2 (re,im) registers -> v_pk_fma_f32.
// s = lane*16 + r ; qubit q <-> s-bit (9-q). Bits 0..3: in-register pairs.
// Bits 4..9: cross-lane via DPP (xor1/2/4/8), ds_swizzle(xor16),
// shfl_xor(xor32). No LDS, no __syncthreads.
//
// R1-R5: VGPR-spill saga -> fix: readfirstlane wave-uniform coeffs to SGPRs.
// R6: 124us. R7/R8: xor1..8 -> DPP, xor16 -> ds_swizzle, xor32 -> shfl
//     (ds_swizzle can't cross 32 lanes) -> 105us, VALUBusy 77%.
// R9: packed float2 state -> pk_fma -> 90us, spill 0, VALUBusy 73%.
// R10: the ~2000 serial-uniform VALU slots/wave spent computing 30 gate
//     matrices (sincos + complex products, identical in all 64 lanes) are
//     parallelized ACROSS lanes: lane g computes gate g's 8 coeffs
//     (~90 divergent-parallel ops), application reads them with
//     v_readlane (240 ops) straight into SGPRs.

typedef float v2 __attribute__((ext_vector_type(2)));

// ---- cross-lane xor via DPP where possible ----
template<int CTRL>
__device__ __forceinline__ float dppf(float v) {
  return __int_as_float(__builtin_amdgcn_update_dpp(
      0, __float_as_int(v), CTRL, 0xF, 0xF, true));
}

template<int LM>
__device__ __forceinline__ float xshfl(float v) {
  if constexpr (LM == 1) {
    return dppf<0xB1>(v);               // quad_perm [1,0,3,2]
  } else if constexpr (LM == 2) {
    return dppf<0x4E>(v);               // quad_perm [2,3,0,1]
  } else if constexpr (LM == 4) {
    return dppf<0x141>(dppf<0x1B>(v));  // xor7(half_mirror) ∘ xor3(quad_perm)
  } else if constexpr (LM == 8) {
    return dppf<0x128>(v);              // row_ror:8 == xor8 within row16
  } else if constexpr (LM == 16) {
    return __int_as_float(__builtin_amdgcn_ds_swizzle(__float_as_int(v), 0x401F));
  } else {
    return __shfl_xor(v, 32);           // ds_bpermute crosses the 32-lane halves
  }
}

template<int LM>
__device__ __forceinline__ v2 xshfl2(v2 v) {
  v2 r; r.x = xshfl<LM>(v.x); r.y = xshfl<LM>(v.y); return r;
}

__device__ __forceinline__ float wred(float v) {
  v += xshfl<1>(v);
  v += xshfl<2>(v);
  v += xshfl<4>(v);
  v += xshfl<8>(v);
  v += xshfl<16>(v);
  v += xshfl<32>(v);
  return v;
}

// force a wave-uniform float into an SGPR
__device__ __forceinline__ float rfl(float x) {
  return __int_as_float(__builtin_amdgcn_readfirstlane(__float_as_int(x)));
}

// tanh(x) = 1 - 2/(exp(2x)+1); __expf saturates correctly at +-inf
__device__ __forceinline__ float fast_tanh(float x) {
  return 1.0f - 2.0f / (__expf(2.0f * x) + 1.0f);
}

// i * a  as packed pair: (re,im) -> (-im, re)
__device__ __forceinline__ v2 sneg(v2 a) {
  v2 r; r.x = -a.y; r.y = a.x; return r;
}

template<int BIT>
__device__ __forceinline__ void gate_apply(v2 (&st)[16], int lane,
    float m00r, float m00i, float m01r, float m01i,
    float m10r, float m10i, float m11r, float m11i) {
  if constexpr (BIT < 4) {
    #pragma unroll
    for (int r0 = 0; r0 < 16; ++r0) {
      if ((r0 & (1 << BIT)) == 0) {
        const int r1 = r0 | (1 << BIT);
        const v2 a0 = st[r0], a1 = st[r1];
        const v2 s0 = sneg(a0), s1 = sneg(a1);
        st[r0] = m00r*a0 + m00i*s0 + m01r*a1 + m01i*s1;
        st[r1] = m10r*a0 + m10i*s0 + m11r*a1 + m11i*s1;
      }
    }
  } else {
    constexpr int lm = 1 << (BIT - 4);
    const bool hi = (lane & lm) != 0;
    // own-amp coeff / partner-amp coeff selected once per gate
    const float cAr = hi ? m11r : m00r, cAi = hi ? m11i : m00i;
    const float cBr = hi ? m10r : m01r, cBi = hi ? m10i : m01i;
    #pragma unroll
    for (int r = 0; r < 16; ++r) {
      const v2 p = xshfl2<lm>(st[r]);
      const v2 a = st[r];
      st[r] = cAr*a + cAi*sneg(a) + cBr*p + cBi*sneg(p);
    }
  }
}

// new[s] = old[ s ^ (ctrlbit(s) ? tgtmask : 0) ]
template<int CB, int TB>
__device__ __forceinline__ void cnot_apply(v2 (&st)[16], int lane) {
  if constexpr (CB >= 4 && TB >= 4) {
    constexpr int lm = 1 << (TB - 4);
    const bool c1 = (lane & (1 << (CB - 4))) != 0;
    #pragma unroll
    for (int r = 0; r < 16; ++r) {
      const v2 p = xshfl2<lm>(st[r]);
      st[r].x = c1 ? p.x : st[r].x;
      st[r].y = c1 ? p.y : st[r].y;
    }
  } else if constexpr (CB >= 4 && TB < 4) {
    const bool c1 = (lane & (1 << (CB - 4))) != 0;
    #pragma unroll
    for (int r0 = 0; r0 < 16; ++r0) {
      if ((r0 & (1 << TB)) == 0) {
        const int r1 = r0 | (1 << TB);
        const v2 a = st[r0], b = st[r1];
        st[r0].x = c1 ? b.x : a.x;  st[r0].y = c1 ? b.y : a.y;
        st[r1].x = c1 ? a.x : b.x;  st[r1].y = c1 ? a.y : b.y;
      }
    }
  } else if constexpr (CB < 4 && TB >= 4) {
    constexpr int lm = 1 << (TB - 4);
    #pragma unroll
    for (int r = 0; r < 16; ++r) {
      if ((r & (1 << CB)) != 0) {     // compile-time per unrolled r
        st[r] = xshfl2<lm>(st[r]);
      }
    }
  } else {
    #pragma unroll
    for (int r0 = 0; r0 < 16; ++r0) {
      if ((r0 & (1 << CB)) != 0 && (r0 & (1 << TB)) == 0) {
        const int r1 = r0 | (1 << TB);
        const v2 t = st[r0]; st[r0] = st[r1]; st[r1] = t;
      }
    }
  }
}

// half_ang(s) = 0.5*pi * sum_p J_p * mask_p(s),  mask = +1 iff bits differ = -z_i z_j
// decomposed: C(lane) [high-high] + d[j]*z_j(r) [high-low] + e[ij]*z_i(r)z_j(r) [low-low]
template<int I, int J>
__device__ __forceinline__ void pair_accum(float t, int lane, float& Cc,
                                           float (&dcf)[4], float (&ecf)[6]) {
  if constexpr (J <= 5) {
    const bool diff = (((lane >> (5 - I)) ^ (lane >> (5 - J))) & 1) != 0;
    Cc += diff ? -t : t;            // t * z_i(lane) * z_j(lane)
  } else if constexpr (I <= 5) {
    const bool b = ((lane >> (5 - I)) & 1) != 0;
    dcf[J - 6] += b ? -t : t;       // t * z_i(lane)
  } else {
    constexpr int eb = (I == 6) ? 0 : (I == 7) ? 3 : 5;
    ecf[eb + (J - I - 1)] = rfl(t); // wave-uniform -> SGPR
  }
}

#define PAIR(i, j) { \
  const v2 pr_ = ym[i] * ym[j]; \
  float dot_ = wred(pr_.x + pr_.y) * (1.0f/127.0f); \
  const float t_ = -1.5707963267948966f * fast_tanh(dot_ * expA); \
  pair_accum<i, j>(t_, lane, Cc, dcoef, ecoef); }

// read lane g's coefficient into an SGPR
#define RLg(g_, x_) __int_as_float(__builtin_amdgcn_readlane(__float_as_int(x_), (g_)))

// apply gate g (coeffs live in lane g's Mxx registers) to qubit q
#define GATE(g_, q_) \
  gate_apply<9 - (q_)>(st, lane, \
      RLg(g_, Mr00), RLg(g_, Mi00), RLg(g_, Mr01), RLg(g_, Mi01), \
      RLg(g_, Mr10), RLg(g_, Mi10), RLg(g_, Mr11), RLg(g_, Mi11));

#define CNOT(ctrl, rng) cnot_apply<9 - (ctrl), 9 - ((((ctrl) + (rng)) % 10))>(st, lane);

extern "C" __global__ void __launch_bounds__(256, 2)
qhl_kernel(const float* __restrict__ c_kt, const float* __restrict__ dc_kt,
           const float* __restrict__ vw,  const float* __restrict__ w_proj,
           const float* __restrict__ b_proj, const float* __restrict__ log_alpha,
           float* __restrict__ out) {
  const int wave = threadIdx.x >> 6;
  const int lane = threadIdx.x & 63;
  const int bid  = blockIdx.x * 4 + wave;

  const float* c   = c_kt  + (size_t)bid * 1280;
  const float* dcp = dc_kt + (size_t)bid * 1280;

  // ---- per-lane gate-matrix precompute: lane g -> gate g = (l=g/10, q=g%10)
  // M = Rot(l,q) for l==0; M = Rot(l,q)·EncHalf(q) for l>=1. All lanes do
  // ~90 ops in parallel instead of every lane doing ~2000 serial-uniform.
  float Mr00, Mi00, Mr01, Mi01, Mr10, Mi10, Mr11, Mi11;
  {
    const int g = lane < 30 ? lane : 0;
    const int l = g / 10, q = g - l * 10;
    const float w0 = vw[g*3+0], w1 = vw[g*3+1], w2 = vw[g*3+2];
    float cY, sY; __sincosf(0.5f*w1, &sY, &cY);
    float ca, sa; __sincosf(0.5f*(w0+w2), &sa, &ca);
    float cb, sb; __sincosf(0.5f*(w0-w2), &sb, &cb);
    const float r00r =  cY*ca, r00i = -cY*sa, r01r = -sY*cb, r01i = -sY*sb;
    const float r10r =  sY*cb, r10i = -sY*sb, r11r =  cY*ca, r11i =  cY*sa;
    if (l == 0) {
      Mr00 = r00r; Mi00 = r00i; Mr01 = r01r; Mi01 = r01i;
      Mr10 = r10r; Mi10 = r10i; Mr11 = r11r; Mi11 = r11i;
    } else {
      const float thq = c[1270 + q], phq = dcp[1270 + q];
      float cy, sy; __sincosf(0.25f * thq, &sy, &cy);
      float cz, sz; __sincosf(0.25f * phq, &sz, &cz);
      const float e00r =  cy*cz, e00i = -cy*sz, e01r = -sy*cz, e01i =  sy*sz;
      const float e10r =  sy*cz, e10i =  sy*sz, e11r =  cy*cz, e11i =  cy*sz;
      Mr00 = r00r*e00r - r00i*e00i + r01r*e10r - r01i*e10i;
      Mi00 = r00r*e00i + r00i*e00r + r01r*e10i + r01i*e10r;
      Mr01 = r00r*e01r - r00i*e01i + r01r*e11r - r01i*e11i;
      Mi01 = r00r*e01i + r00i*e01r + r01r*e11i + r01i*e11r;
      Mr10 = r10r*e00r - r10i*e00i + r11r*e10r - r11i*e10i;
      Mi10 = r10r*e00i + r10i*e00r + r11r*e10i + r11i*e10r;
      Mr11 = r10r*e01r - r10i*e01i + r11r*e11r - r11i*e11i;
      Mi11 = r10r*e01i + r10i*e01r + r11r*e11i + r11i*e11r;
    }
  }

  // ---- correlation: rows packed as (row_lane, row_lane+64) float2 pairs ----
  v2 ym[10];
  {
    const float2* c0 = (const float2*)(c   + lane * 10);
    const float2* d0 = (const float2*)(dcp + lane * 10);
    const float2* c1 = (const float2*)(c   + (lane + 64) * 10);
    const float2* d1 = (const float2*)(dcp + (lane + 64) * 10);
    #pragma unroll
    for (int k = 0; k < 5; ++k) {
      const float2 a0 = c0[k], b0 = d0[k], a1 = c1[k], b1 = d1[k];
      ym[2*k].x   = a0.x + 0.5f * b0.x;  ym[2*k].y   = a1.x + 0.5f * b1.x;
      ym[2*k+1].x = a0.y + 0.5f * b0.y;  ym[2*k+1].y = a1.y + 0.5f * b1.y;
    }
  }
  #pragma unroll
  for (int k = 0; k < 10; ++k) {
    const float mean = wred(ym[k].x + ym[k].y) * (1.0f / 128.0f);
    ym[k].x -= mean; ym[k].y -= mean;
    const v2 sq = ym[k] * ym[k];
    const float ss = wred(sq.x + sq.y);
    // rs = 1 / max(sqrt(ss/127), 1e-8)
    const float rs = fminf(__builtin_amdgcn_rsqf(ss * (1.0f / 127.0f)), 1e8f);
    ym[k] *= rs;
  }

  const float expA = rfl(__expf(log_alpha[0]));
  float Cc = 0.0f, dcoef[4] = {0, 0, 0, 0}, ecoef[6];
  PAIR(0,1) PAIR(0,2) PAIR(0,3) PAIR(0,4) PAIR(0,5) PAIR(0,6) PAIR(0,7) PAIR(0,8) PAIR(0,9)
  PAIR(1,2) PAIR(1,3) PAIR(1,4) PAIR(1,5) PAIR(1,6) PAIR(1,7) PAIR(1,8) PAIR(1,9)
  PAIR(2,3) PAIR(2,4) PAIR(2,5) PAIR(2,6) PAIR(2,7) PAIR(2,8) PAIR(2,9)
  PAIR(3,4) PAIR(3,5) PAIR(3,6) PAIR(3,7) PAIR(3,8) PAIR(3,9)
  PAIR(4,5) PAIR(4,6) PAIR(4,7) PAIR(4,8) PAIR(4,9)
  PAIR(5,6) PAIR(5,7) PAIR(5,8) PAIR(5,9)
  PAIR(6,7) PAIR(6,8) PAIR(6,9)
  PAIR(7,8) PAIR(7,9)
  PAIR(8,9)

  // ---- encoding angles: wave-uniform -> force into SGPRs ----
  float th[10], ph[10];
  #pragma unroll
  for (int q = 0; q < 10; ++q) {
    th[q] = rfl(c[1270 + q]);
    ph[q] = rfl(dcp[1270 + q]);
  }

  // ---- closed-form initial state: (prod_q RZ(ph)RY(th)|0>) * e^{i h} ----
  // single-qubit: RZ(ph)RY(th)|0> = (cos(th/2) e^{-i ph/2}, sin(th/2) e^{+i ph/2})
  // qubits 0..5 <-> lane bits 5..0 (product -> L, per lane)
  // qubits 6..9 <-> r bits 3..0    (product -> R[r], via uniform tables)
  v2 st[16];
  {
    v2 L; L.x = 1.0f; L.y = 0.0f;
    #pragma unroll
    for (int q = 0; q < 6; ++q) {
      float cy, sy; __sincosf(0.5f * th[q], &sy, &cy);
      float cz, sz; __sincosf(0.5f * ph[q], &sz, &cz);
      const bool b = ((lane >> (5 - q)) & 1) != 0;
      const float zr = b ? sy * cz : cy * cz;
      const float zi = b ? sy * sz : -cy * sz;
      L = zr * L + zi * sneg(L);
    }
    float ar[4][2], ai[4][2];
    #pragma unroll
    for (int t = 0; t < 4; ++t) {
      float cy, sy; __sincosf(0.5f * th[6 + t], &sy, &cy);
      float cz, sz; __sincosf(0.5f * ph[6 + t], &sz, &cz);
      ar[t][0] = rfl(cy * cz);  ai[t][0] = rfl(-cy * sz);
      ar[t][1] = rfl(sy * cz);  ai[t][1] = rfl( sy * sz);
    }
    #pragma unroll
    for (int r = 0; r < 16; ++r) {
      const int b3 = (r >> 3) & 1, b2 = (r >> 2) & 1, b1 = (r >> 1) & 1, b0 = r & 1;
      // R = a0[b3]*a1[b2]*a2[b1]*a3[b0]  (all uniform -> SGPR math folded)
      float Rr = ar[0][b3], Ri = ai[0][b3];
      float t1 = Rr * ar[1][b2] - Ri * ai[1][b2];
      Ri = Rr * ai[1][b2] + Ri * ar[1][b2]; Rr = t1;
      t1 = Rr * ar[2][b1] - Ri * ai[2][b1];
      Ri = Rr * ai[2][b1] + Ri * ar[2][b1]; Rr = t1;
      t1 = Rr * ar[3][b0] - Ri * ai[3][b0];
      Ri = Rr * ai[3][b0] + Ri * ar[3][b0]; Rr = t1;
      // ZZ phase angle
      float h = Cc;
      h += b3 ? -dcoef[0] : dcoef[0];
      h += b2 ? -dcoef[1] : dcoef[1];
      h += b1 ? -dcoef[2] : dcoef[2];
      h += b0 ? -dcoef[3] : dcoef[3];
      h += (b3 ^ b2) ? -ecoef[0] : ecoef[0];
      h += (b3 ^ b1) ? -ecoef[1] : ecoef[1];
      h += (b3 ^ b0) ? -ecoef[2] : ecoef[2];
      h += (b2 ^ b1) ? -ecoef[3] : ecoef[3];
      h += (b2 ^ b0) ? -ecoef[4] : ecoef[4];
      h += (b1 ^ b0) ? -ecoef[5] : ecoef[5];
      float sn, cs; __sincosf(h, &sn, &cs);
      // st = (e^{ih} * L) * R
      const v2 p = cs * L + sn * sneg(L);
      st[r] = Rr * p + Ri * sneg(p);
    }
  }

  // ---- layer 0 ----
  GATE(0,0) GATE(1,1) GATE(2,2) GATE(3,3) GATE(4,4)
  GATE(5,5) GATE(6,6) GATE(7,7) GATE(8,8) GATE(9,9)
  CNOT(0,1) CNOT(1,1) CNOT(2,1) CNOT(3,1) CNOT(4,1)
  CNOT(5,1) CNOT(6,1) CNOT(7,1) CNOT(8,1) CNOT(9,1)
  // ---- re-encode(0.5) fused with layer-1 Rot ----
  GATE(10,0) GATE(11,1) GATE(12,2) GATE(13,3) GATE(14,4)
  GATE(15,5) GATE(16,6) GATE(17,7) GATE(18,8) GATE(19,9)
  CNOT(0,2) CNOT(1,2) CNOT(2,2) CNOT(3,2) CNOT(4,2)
  CNOT(5,2) CNOT(6,2) CNOT(7,2) CNOT(8,2) CNOT(9,2)
  // ---- re-encode(0.5) fused with layer-2 Rot ----
  GATE(20,0) GATE(21,1) GATE(22,2) GATE(23,3) GATE(24,4)
  GATE(25,5) GATE(26,6) GATE(27,7) GATE(28,8) GATE(29,9)
  CNOT(0,3) CNOT(1,3) CNOT(2,3) CNOT(3,3) CNOT(4,3)
  CNOT(5,3) CNOT(6,3) CNOT(7,3) CNOT(8,3) CNOT(9,3)

  // ---- measurement: Z expvals then 3-action projection ----
  float P = 0.0f, e6 = 0.0f, e7 = 0.0f, e8 = 0.0f, e9 = 0.0f;
  #pragma unroll
  for (int r = 0; r < 16; ++r) {
    const v2 sq = st[r] * st[r];
    const float pp = sq.x + sq.y;
    P  += pp;
    e6 += (r & 8) ? -pp : pp;
    e7 += (r & 4) ? -pp : pp;
    e8 += (r & 2) ? -pp : pp;
    e9 += (r & 1) ? -pp : pp;
  }
  float ev[10];
  ev[0] = (lane & 32) ? -P : P;
  ev[1] = (lane & 16) ? -P : P;
  ev[2] = (lane &  8) ? -P : P;
  ev[3] = (lane &  4) ? -P : P;
  ev[4] = (lane &  2) ? -P : P;
  ev[5] = (lane &  1) ? -P : P;
  ev[6] = e6; ev[7] = e7; ev[8] = e8; ev[9] = e9;
  #pragma unroll
  for (int i = 0; i < 10; ++i) ev[i] = wred(ev[i]);

  if (lane < 3) {
    float acc = b_proj[lane];
    #pragma unroll
    for (int i = 0; i < 10; ++i) acc += w_proj[lane * 10 + i] * ev[i];
    out[(size_t)bid * 3 + lane] = acc;
  }
}

extern "C" void kernel_launch(void* const* d_in, const int* in_sizes, int n_in,
                              void* d_out, int out_size, void* d_ws, size_t ws_size,
                              hipStream_t stream) {
  (void)in_sizes; (void)n_in; (void)d_ws; (void)ws_size; (void)out_size;
  const float* c_kt      = (const float*)d_in[0];
  const float* dc_kt     = (const float*)d_in[1];
  const float* vw        = (const float*)d_in[2];
  const float* w_proj    = (const float*)d_in[3];
  const float* b_proj    = (const float*)d_in[4];
  const float* log_alpha = (const float*)d_in[5];
  float* out = (float*)d_out;
  // 4096 batch elems, 1 wave each, 4 waves per 256-thread block
  qhl_kernel<<<dim3(1024), dim3(256), 0, stream>>>(c_kt, dc_kt, vw, w_proj,
                                                   b_proj, log_alpha, out);
}

// Round 11
// 130.987 us; speedup vs baseline: 1.8824x; 1.0876x over previous
//
#include <hip/hip_runtime.h>

// One wave (64 lanes) per batch element. State: 1024 complex amps = 16/lane
// held as PACKED float2 (re,im) registers -> v_pk_fma_f32.
// s = lane*16 + r ; qubit q <-> s-bit (9-q). Bits 0..3: in-register pairs.
// Bits 4..9: cross-lane via DPP (xor1/2/4/8), ds_swizzle(xor16),
// shfl_xor(xor32). No LDS, no __syncthreads.
//
// R6: SGPR-ify uniform gate coeffs -> 124us. R7/R8: DPP shuffles -> 105us.
// R9: packed float2 state (pk_fma) -> 90us. R10: per-lane gate-matrix
//     precompute + v_readlane -> 72us, VGPR 64, zero spill, VALUBusy 74%.
// R11: kill the serial wave-reductions: multi-value FUNNEL reductions
//     (48->24->12->6->3->2->1; DPP stages first, DS stages last on <=4
//     values). 45 pair-dots land one-per-lane -> tanh runs lane-parallel,
//     redistributed via readlane. Same funnel for mean/ss/measurement.
//     Init R-products (uniform per-r) also lane-parallelized.

typedef float v2 __attribute__((ext_vector_type(2)));

// ---- cross-lane xor via DPP where possible ----
template<int CTRL>
__device__ __forceinline__ float dppf(float v) {
  return __int_as_float(__builtin_amdgcn_update_dpp(
      0, __float_as_int(v), CTRL, 0xF, 0xF, true));
}

template<int LM>
__device__ __forceinline__ float xshfl(float v) {
  if constexpr (LM == 1) {
    return dppf<0xB1>(v);               // quad_perm [1,0,3,2]
  } else if constexpr (LM == 2) {
    return dppf<0x4E>(v);               // quad_perm [2,3,0,1]
  } else if constexpr (LM == 4) {
    return dppf<0x141>(dppf<0x1B>(v));  // xor7(half_mirror) ∘ xor3(quad_perm)
  } else if constexpr (LM == 8) {
    return dppf<0x128>(v);              // row_ror:8 == xor8 within row16
  } else if constexpr (LM == 16) {
    return __int_as_float(__builtin_amdgcn_ds_swizzle(__float_as_int(v), 0x401F));
  } else {
    return __shfl_xor(v, 32);           // ds_bpermute crosses the 32-lane halves
  }
}

template<int LM>
__device__ __forceinline__ v2 xshfl2(v2 v) {
  v2 r; r.x = xshfl<LM>(v.x); r.y = xshfl<LM>(v.y); return r;
}

// ---- multi-value funnel reduction stage: NP pairs (i, i+NP) across bit B.
// lane with (lane&B)==0 keeps slot i, ==1 keeps slot i+NP; both get the sum.
template<int B, int NP>
__device__ __forceinline__ void fstage(float* p, int lane) {
  #pragma unroll
  for (int i = 0; i < NP; ++i) {
    const float send = (lane & B) ? p[i] : p[i + NP];
    const float recv = xshfl<B>(send);
    const float keep = (lane & B) ? p[i + NP] : p[i];
    p[i] = keep + recv;
  }
}

// after stages B=1(NP24),2(12),4(6),8(3),16(2),32(1): lane l holds original
// slot (l&1)*24+(l&2?12:0)+(l&4?6:0)+(l&8?3:0)+(l&16?2:0)+(l&32?1:0).
// holder lane for slot v (avoiding padded branches):
constexpr int holder_lane45(int v) {
  const int a = v >= 24; int r = v - 24 * a;
  const int b = r >= 12; r -= 12 * b;
  const int c = r >= 6;  r -= 6 * c;
  const int d = r >= 3;  r -= 3 * d;
  const int e = r >= 2;  r -= 2 * e;
  return a | (b << 1) | (c << 2) | (d << 3) | (e << 4) | (r << 5);
}

// 10-value funnel: stages B=1(NP5),2(3),4(2),8(1) then += xor16, += xor32.
// lane l (bits 0..3) holds slot (l&1)*5+(l&2?3:0)+(l&4?2:0)+(l&8?1:0).
constexpr int holder_lane10(int v) {
  const int a = v >= 5; int r = v - 5 * a;
  const int b = r >= 3; r -= 3 * b;
  const int c = r >= 2; r -= 2 * c;
  return a | (b << 1) | (c << 2) | (r << 3);
}

__device__ __forceinline__ void funnel10(float* p, int lane) {
  fstage<1, 5>(p, lane);
  p[5] = 0.0f;            // unused-high pad for next stage
  fstage<2, 3>(p, lane);
  p[3] = 0.0f;
  fstage<4, 2>(p, lane);
  fstage<8, 1>(p, lane);
  p[0] += xshfl<16>(p[0]);
  p[0] += xshfl<32>(p[0]);
}

// force a wave-uniform float into an SGPR
__device__ __forceinline__ float rfl(float x) {
  return __int_as_float(__builtin_amdgcn_readfirstlane(__float_as_int(x)));
}

// read lane g's value (uniform result -> SGPR)
#define RLg(g_, x_) __int_as_float(__builtin_amdgcn_readlane(__float_as_int(x_), (g_)))

// tanh(x) = 1 - 2/(exp(2x)+1); __expf saturates correctly at +-inf
__device__ __forceinline__ float fast_tanh(float x) {
  return 1.0f - 2.0f / (__expf(2.0f * x) + 1.0f);
}

// i * a  as packed pair: (re,im) -> (-im, re)
__device__ __forceinline__ v2 sneg(v2 a) {
  v2 r; r.x = -a.y; r.y = a.x; return r;
}

template<int BIT>
__device__ __forceinline__ void gate_apply(v2 (&st)[16], int lane,
    float m00r, float m00i, float m01r, float m01i,
    float m10r, float m10i, float m11r, float m11i) {
  if constexpr (BIT < 4) {
    #pragma unroll
    for (int r0 = 0; r0 < 16; ++r0) {
      if ((r0 & (1 << BIT)) == 0) {
        const int r1 = r0 | (1 << BIT);
        const v2 a0 = st[r0], a1 = st[r1];
        const v2 s0 = sneg(a0), s1 = sneg(a1);
        st[r0] = m00r*a0 + m00i*s0 + m01r*a1 + m01i*s1;
        st[r1] = m10r*a0 + m10i*s0 + m11r*a1 + m11i*s1;
      }
    }
  } else {
    constexpr int lm = 1 << (BIT - 4);
    const bool hi = (lane & lm) != 0;
    const float cAr = hi ? m11r : m00r, cAi = hi ? m11i : m00i;
    const float cBr = hi ? m10r : m01r, cBi = hi ? m10i : m01i;
    #pragma unroll
    for (int r = 0; r < 16; ++r) {
      const v2 p = xshfl2<lm>(st[r]);
      const v2 a = st[r];
      st[r] = cAr*a + cAi*sneg(a) + cBr*p + cBi*sneg(p);
    }
  }
}

// new[s] = old[ s ^ (ctrlbit(s) ? tgtmask : 0) ]
template<int CB, int TB>
__device__ __forceinline__ void cnot_apply(v2 (&st)[16], int lane) {
  if constexpr (CB >= 4 && TB >= 4) {
    constexpr int lm = 1 << (TB - 4);
    const bool c1 = (lane & (1 << (CB - 4))) != 0;
    #pragma unroll
    for (int r = 0; r < 16; ++r) {
      const v2 p = xshfl2<lm>(st[r]);
      st[r].x = c1 ? p.x : st[r].x;
      st[r].y = c1 ? p.y : st[r].y;
    }
  } else if constexpr (CB >= 4 && TB < 4) {
    const bool c1 = (lane & (1 << (CB - 4))) != 0;
    #pragma unroll
    for (int r0 = 0; r0 < 16; ++r0) {
      if ((r0 & (1 << TB)) == 0) {
        const int r1 = r0 | (1 << TB);
        const v2 a = st[r0], b = st[r1];
        st[r0].x = c1 ? b.x : a.x;  st[r0].y = c1 ? b.y : a.y;
        st[r1].x = c1 ? a.x : b.x;  st[r1].y = c1 ? a.y : b.y;
      }
    }
  } else if constexpr (CB < 4 && TB >= 4) {
    constexpr int lm = 1 << (TB - 4);
    #pragma unroll
    for (int r = 0; r < 16; ++r) {
      if ((r & (1 << CB)) != 0) {
        st[r] = xshfl2<lm>(st[r]);
      }
    }
  } else {
    #pragma unroll
    for (int r0 = 0; r0 < 16; ++r0) {
      if ((r0 & (1 << CB)) != 0 && (r0 & (1 << TB)) == 0) {
        const int r1 = r0 | (1 << TB);
        const v2 t = st[r0]; st[r0] = st[r1]; st[r1] = t;
      }
    }
  }
}

// half_ang decomposition: C(lane) [hi-hi] + d[j]*z_j(r) [hi-lo] + e[ij] [lo-lo]
template<int I, int J>
__device__ __forceinline__ void pair_accum(float t, int lane, float& Cc,
                                           float (&dcf)[4], float (&ecf)[6]) {
  if constexpr (J <= 5) {
    const bool diff = (((lane >> (5 - I)) ^ (lane >> (5 - J))) & 1) != 0;
    Cc += diff ? -t : t;
  } else if constexpr (I <= 5) {
    const bool b = ((lane >> (5 - I)) & 1) != 0;
    dcf[J - 6] += b ? -t : t;
  } else {
    constexpr int eb = (I == 6) ? 0 : (I == 7) ? 3 : 5;
    ecf[eb + (J - I - 1)] = t;      // already SGPR-uniform (readlane)
  }
}

#define PACC(v_, i_, j_) pair_accum<i_, j_>(RLg(holder_lane45(v_), tl), lane, Cc, dcoef, ecoef);

#define GATE(g_, q_) \
  gate_apply<9 - (q_)>(st, lane, \
      RLg(g_, Mr00), RLg(g_, Mi00), RLg(g_, Mr01), RLg(g_, Mi01), \
      RLg(g_, Mr10), RLg(g_, Mi10), RLg(g_, Mr11), RLg(g_, Mi11));

#define CNOT(ctrl, rng) cnot_apply<9 - (ctrl), 9 - ((((ctrl) + (rng)) % 10))>(st, lane);

extern "C" __global__ void __launch_bounds__(256, 2)
qhl_kernel(const float* __restrict__ c_kt, const float* __restrict__ dc_kt,
           const float* __restrict__ vw,  const float* __restrict__ w_proj,
           const float* __restrict__ b_proj, const float* __restrict__ log_alpha,
           float* __restrict__ out) {
  const int wave = threadIdx.x >> 6;
  const int lane = threadIdx.x & 63;
  const int bid  = blockIdx.x * 4 + wave;

  const float* c   = c_kt  + (size_t)bid * 1280;
  const float* dcp = dc_kt + (size_t)bid * 1280;

  // ---- per-lane gate-matrix precompute: lane g -> gate g = (l=g/10, q=g%10)
  float Mr00, Mi00, Mr01, Mi01, Mr10, Mi10, Mr11, Mi11;
  {
    const int g = lane < 30 ? lane : 0;
    const int l = g / 10, q = g - l * 10;
    const float w0 = vw[g*3+0], w1 = vw[g*3+1], w2 = vw[g*3+2];
    float cY, sY; __sincosf(0.5f*w1, &sY, &cY);
    float ca, sa; __sincosf(0.5f*(w0+w2), &sa, &ca);
    float cb, sb; __sincosf(0.5f*(w0-w2), &sb, &cb);
    const float r00r =  cY*ca, r00i = -cY*sa, r01r = -sY*cb, r01i = -sY*sb;
    const float r10r =  sY*cb, r10i = -sY*sb, r11r =  cY*ca, r11i =  cY*sa;
    if (l == 0) {
      Mr00 = r00r; Mi00 = r00i; Mr01 = r01r; Mi01 = r01i;
      Mr10 = r10r; Mi10 = r10i; Mr11 = r11r; Mi11 = r11i;
    } else {
      const float thq = c[1270 + q], phq = dcp[1270 + q];
      float cy, sy; __sincosf(0.25f * thq, &sy, &cy);
      float cz, sz; __sincosf(0.25f * phq, &sz, &cz);
      const float e00r =  cy*cz, e00i = -cy*sz, e01r = -sy*cz, e01i =  sy*sz;
      const float e10r =  sy*cz, e10i =  sy*sz, e11r =  cy*cz, e11i =  cy*sz;
      Mr00 = r00r*e00r - r00i*e00i + r01r*e10r - r01i*e10i;
      Mi00 = r00r*e00i + r00i*e00r + r01r*e10i + r01i*e10r;
      Mr01 = r00r*e01r - r00i*e01i + r01r*e11r - r01i*e11i;
      Mi01 = r00r*e01i + r00i*e01r + r01r*e11i + r01i*e11r;
      Mr10 = r10r*e00r - r10i*e00i + r11r*e10r - r11i*e10i;
      Mi10 = r10r*e00i + r10i*e00r + r11r*e10i + r11i*e10r;
      Mr11 = r10r*e01r - r10i*e01i + r11r*e11r - r11i*e11i;
      Mi11 = r10r*e01i + r10i*e01r + r11r*e11i + r11i*e11r;
    }
  }

  // ---- correlation rows packed as (t=lane, t=lane+64) float2 pairs ----
  v2 ym[10];
  {
    const float2* c0 = (const float2*)(c   + lane * 10);
    const float2* d0 = (const float2*)(dcp + lane * 10);
    const float2* c1 = (const float2*)(c   + (lane + 64) * 10);
    const float2* d1 = (const float2*)(dcp + (lane + 64) * 10);
    #pragma unroll
    for (int k = 0; k < 5; ++k) {
      const float2 a0 = c0[k], b0 = d0[k], a1 = c1[k], b1 = d1[k];
      ym[2*k].x   = a0.x + 0.5f * b0.x;  ym[2*k].y   = a1.x + 0.5f * b1.x;
      ym[2*k+1].x = a0.y + 0.5f * b0.y;  ym[2*k+1].y = a1.y + 0.5f * b1.y;
    }
  }

  // ---- row stats via 10-value funnels ----
  {
    float mb[6];
    float m10[10];
    #pragma unroll
    for (int k = 0; k < 10; ++k) m10[k] = ym[k].x + ym[k].y;
    // first stage on the 10-array, rest in mb[6]
    #pragma unroll
    for (int i = 0; i < 5; ++i) {
      const float send = (lane & 1) ? m10[i] : m10[i + 5];
      const float recv = xshfl<1>(send);
      const float keep = (lane & 1) ? m10[i + 5] : m10[i];
      mb[i] = keep + recv;
    }
    mb[5] = 0.0f;
    fstage<2, 3>(mb, lane);
    mb[3] = 0.0f;
    fstage<4, 2>(mb, lane);
    fstage<8, 1>(mb, lane);
    mb[0] += xshfl<16>(mb[0]);
    mb[0] += xshfl<32>(mb[0]);
    mb[0] *= (1.0f / 128.0f);
    #pragma unroll
    for (int k = 0; k < 10; ++k) {
      const float mk = RLg(holder_lane10(k), mb[0]);
      ym[k].x -= mk; ym[k].y -= mk;
    }
    // sum of squares
    float s10[10];
    #pragma unroll
    for (int k = 0; k < 10; ++k) { const v2 sq = ym[k] * ym[k]; s10[k] = sq.x + sq.y; }
    #pragma unroll
    for (int i = 0; i < 5; ++i) {
      const float send = (lane & 1) ? s10[i] : s10[i + 5];
      const float recv = xshfl<1>(send);
      const float keep = (lane & 1) ? s10[i + 5] : s10[i];
      mb[i] = keep + recv;
    }
    mb[5] = 0.0f;
    fstage<2, 3>(mb, lane);
    mb[3] = 0.0f;
    fstage<4, 2>(mb, lane);
    fstage<8, 1>(mb, lane);
    mb[0] += xshfl<16>(mb[0]);
    mb[0] += xshfl<32>(mb[0]);
    // rs = 1 / max(sqrt(ss/127), 1e-8), computed on every lane of its value
    const float rsv = fminf(__builtin_amdgcn_rsqf(mb[0] * (1.0f / 127.0f)), 1e8f);
    #pragma unroll
    for (int k = 0; k < 10; ++k) {
      const float rk = RLg(holder_lane10(k), rsv);
      ym[k].x *= rk; ym[k].y *= rk;
    }
  }

  // ---- 45 pair dots via one 48-slot funnel; tanh lane-parallel ----
  const float expA = rfl(__expf(log_alpha[0]));
  float Cc = 0.0f, dcoef[4] = {0, 0, 0, 0}, ecoef[6];
  float tl;
  {
    constexpr int PI_[45] = {0,0,0,0,0,0,0,0,0, 1,1,1,1,1,1,1,1, 2,2,2,2,2,2,2,
                             3,3,3,3,3,3, 4,4,4,4,4, 5,5,5,5, 6,6,6, 7,7, 8};
    constexpr int PJ_[45] = {1,2,3,4,5,6,7,8,9, 2,3,4,5,6,7,8,9, 3,4,5,6,7,8,9,
                             4,5,6,7,8,9, 5,6,7,8,9, 6,7,8,9, 7,8,9, 8,9, 9};
    float p[48];
    #pragma unroll
    for (int v = 0; v < 45; ++v) {
      const v2 pr = ym[PI_[v]] * ym[PJ_[v]];
      p[v] = pr.x + pr.y;
    }
    p[45] = 0.0f; p[46] = 0.0f; p[47] = 0.0f;
    fstage<1, 24>(p, lane);
    fstage<2, 12>(p, lane);
    fstage<4, 6>(p, lane);
    fstage<8, 3>(p, lane);
    p[3] = 0.0f;
    fstage<16, 2>(p, lane);
    fstage<32, 1>(p, lane);
    // each lane holds one finished dot; compute its t in parallel
    const float sc = expA * (1.0f / 127.0f);
    tl = -1.5707963267948966f * fast_tanh(p[0] * sc);
  }
  PACC(0,0,1) PACC(1,0,2) PACC(2,0,3) PACC(3,0,4) PACC(4,0,5) PACC(5,0,6) PACC(6,0,7) PACC(7,0,8) PACC(8,0,9)
  PACC(9,1,2) PACC(10,1,3) PACC(11,1,4) PACC(12,1,5) PACC(13,1,6) PACC(14,1,7) PACC(15,1,8) PACC(16,1,9)
  PACC(17,2,3) PACC(18,2,4) PACC(19,2,5) PACC(20,2,6) PACC(21,2,7) PACC(22,2,8) PACC(23,2,9)
  PACC(24,3,4) PACC(25,3,5) PACC(26,3,6) PACC(27,3,7) PACC(28,3,8) PACC(29,3,9)
  PACC(30,4,5) PACC(31,4,6) PACC(32,4,7) PACC(33,4,8) PACC(34,4,9)
  PACC(35,5,6) PACC(36,5,7) PACC(37,5,8) PACC(38,5,9)
  PACC(39,6,7) PACC(40,6,8) PACC(41,6,9)
  PACC(42,7,8) PACC(43,7,9)
  PACC(44,8,9)

  // ---- encoding angles: wave-uniform -> SGPRs ----
  float th[10], ph[10];
  #pragma unroll
  for (int q = 0; q < 10; ++q) {
    th[q] = rfl(c[1270 + q]);
    ph[q] = rfl(dcp[1270 + q]);
  }

  // ---- per-lane R product: lane r computes R_r for qubits 6..9 ----
  float Rr_l, Ri_l;
  {
    const int rr = lane & 15;
    float prr = 1.0f, pri = 0.0f;
    #pragma unroll
    for (int t = 0; t < 4; ++t) {
      float cy, sy; __sincosf(0.5f * th[6 + t], &sy, &cy);
      float cz, sz; __sincosf(0.5f * ph[6 + t], &sz, &cz);
      const bool b = ((rr >> (3 - t)) & 1) != 0;
      const float fr = b ? sy * cz : cy * cz;
      const float fi = b ? sy * sz : -cy * sz;
      const float nr = prr * fr - pri * fi;
      pri = prr * fi + pri * fr;
      prr = nr;
    }
    Rr_l = prr; Ri_l = pri;
  }

  // ---- closed-form initial state: (prod_q RZ(ph)RY(th)|0>) * e^{i h} ----
  v2 st[16];
  {
    v2 L; L.x = 1.0f; L.y = 0.0f;
    #pragma unroll
    for (int q = 0; q < 6; ++q) {
      float cy, sy; __sincosf(0.5f * th[q], &sy, &cy);
      float cz, sz; __sincosf(0.5f * ph[q], &sz, &cz);
      const bool b = ((lane >> (5 - q)) & 1) != 0;
      const float zr = b ? sy * cz : cy * cz;
      const float zi = b ? sy * sz : -cy * sz;
      L = zr * L + zi * sneg(L);
    }
    #pragma unroll
    for (int r = 0; r < 16; ++r) {
      const int b3 = (r >> 3) & 1, b2 = (r >> 2) & 1, b1 = (r >> 1) & 1, b0 = r & 1;
      const float Rr = RLg(r, Rr_l);
      const float Ri = RLg(r, Ri_l);
      // ZZ phase angle
      float h = Cc;
      h += b3 ? -dcoef[0] : dcoef[0];
      h += b2 ? -dcoef[1] : dcoef[1];
      h += b1 ? -dcoef[2] : dcoef[2];
      h += b0 ? -dcoef[3] : dcoef[3];
      h += (b3 ^ b2) ? -ecoef[0] : ecoef[0];
      h += (b3 ^ b1) ? -ecoef[1] : ecoef[1];
      h += (b3 ^ b0) ? -ecoef[2] : ecoef[2];
      h += (b2 ^ b1) ? -ecoef[3] : ecoef[3];
      h += (b2 ^ b0) ? -ecoef[4] : ecoef[4];
      h += (b1 ^ b0) ? -ecoef[5] : ecoef[5];
      float sn, cs; __sincosf(h, &sn, &cs);
      const v2 p = cs * L + sn * sneg(L);
      st[r] = Rr * p + Ri * sneg(p);
    }
  }

  // ---- layer 0 ----
  GATE(0,0) GATE(1,1) GATE(2,2) GATE(3,3) GATE(4,4)
  GATE(5,5) GATE(6,6) GATE(7,7) GATE(8,8) GATE(9,9)
  CNOT(0,1) CNOT(1,1) CNOT(2,1) CNOT(3,1) CNOT(4,1)
  CNOT(5,1) CNOT(6,1) CNOT(7,1) CNOT(8,1) CNOT(9,1)
  // ---- re-encode(0.5) fused with layer-1 Rot ----
  GATE(10,0) GATE(11,1) GATE(12,2) GATE(13,3) GATE(14,4)
  GATE(15,5) GATE(16,6) GATE(17,7) GATE(18,8) GATE(19,9)
  CNOT(0,2) CNOT(1,2) CNOT(2,2) CNOT(3,2) CNOT(4,2)
  CNOT(5,2) CNOT(6,2) CNOT(7,2) CNOT(8,2) CNOT(9,2)
  // ---- re-encode(0.5) fused with layer-2 Rot ----
  GATE(20,0) GATE(21,1) GATE(22,2) GATE(23,3) GATE(24,4)
  GATE(25,5) GATE(26,6) GATE(27,7) GATE(28,8) GATE(29,9)
  CNOT(0,3) CNOT(1,3) CNOT(2,3) CNOT(3,3) CNOT(4,3)
  CNOT(5,3) CNOT(6,3) CNOT(7,3) CNOT(8,3) CNOT(9,3)

  // ---- measurement: Z expvals (10-value funnel) + projection ----
  float P = 0.0f, e6 = 0.0f, e7 = 0.0f, e8 = 0.0f, e9 = 0.0f;
  #pragma unroll
  for (int r = 0; r < 16; ++r) {
    const v2 sq = st[r] * st[r];
    const float pp = sq.x + sq.y;
    P  += pp;
    e6 += (r & 8) ? -pp : pp;
    e7 += (r & 4) ? -pp : pp;
    e8 += (r & 2) ? -pp : pp;
    e9 += (r & 1) ? -pp : pp;
  }
  float mv[10];
  mv[0] = (lane & 32) ? -P : P;
  mv[1] = (lane & 16) ? -P : P;
  mv[2] = (lane &  8) ? -P : P;
  mv[3] = (lane &  4) ? -P : P;
  mv[4] = (lane &  2) ? -P : P;
  mv[5] = (lane &  1) ? -P : P;
  mv[6] = e6; mv[7] = e7; mv[8] = e8; mv[9] = e9;
  {
    float fb[6];
    #pragma unroll
    for (int i = 0; i < 5; ++i) {
      const float send = (lane & 1) ? mv[i] : mv[i + 5];
      const float recv = xshfl<1>(send);
      const float keep = (lane & 1) ? mv[i + 5] : mv[i];
      fb[i] = keep + recv;
    }
    fb[5] = 0.0f;
    fstage<2, 3>(fb, lane);
    fb[3] = 0.0f;
    fstage<4, 2>(fb, lane);
    fstage<8, 1>(fb, lane);
    fb[0] += xshfl<16>(fb[0]);
    fb[0] += xshfl<32>(fb[0]);
    float ev[10];
    #pragma unroll
    for (int k = 0; k < 10; ++k) ev[k] = RLg(holder_lane10(k), fb[0]);
    if (lane < 3) {
      float acc = b_proj[lane];
      #pragma unroll
      for (int i = 0; i < 10; ++i) acc += w_proj[lane * 10 + i] * ev[i];
      out[(size_t)bid * 3 + lane] = acc;
    }
  }
}

extern "C" void kernel_launch(void* const* d_in, const int* in_sizes, int n_in,
                              void* d_out, int out_size, void* d_ws, size_t ws_size,
                              hipStream_t stream) {
  (void)in_sizes; (void)n_in; (void)d_ws; (void)ws_size; (void)out_size;
  const float* c_kt      = (const float*)d_in[0];
  const float* dc_kt     = (const float*)d_in[1];
  const float* vw        = (const float*)d_in[2];
  const float* w_proj    = (const float*)d_in[3];
  const float* b_proj    = (const float*)d_in[4];
  const float* log_alpha = (const float*)d_in[5];
  float* out = (float*)d_out;
  // 4096 batch elems, 1 wave each, 4 waves per 256-thread block
  qhl_kernel<<<dim3(1024), dim3(256), 0, stream>>>(c_kt, dc_kt, vw, w_proj,
                                                   b_proj, log_alpha, out);
}

// Round 12
// 126.563 us; speedup vs baseline: 1.9481x; 1.0350x over previous
//
#include <hip/hip_runtime.h>

// One wave (64 lanes) per batch element. State: 1024 complex amps = 16/lane
// as packed float2 (re,im) -> v_pk_fma_f32. s = lane*16 + r; qubit q <-> s-bit
// (9-q); s bits 0..3 = r, bits 4..9 = lane. No LDS staging, no __syncthreads.
//
// R6 SGPR coeffs 124us; R7/R8 DPP shuffles 105us; R9 packed state 90us;
// R10 lane-parallel gate precompute 72us; R11 funnel reductions 64us.
// R12: ALL 30 CNOTs folded into the gates by GF(2) conjugation:
//   final = U_{Q3} H2 H1 G0, Q_l = P_l...P_1 (compile-time matrices).
//   H gate on qubit q: pairs t, t^m (m = Q^-1 e_b), indicator
//   h = parity(t & row_b(Q)). SU(2) form (m11=m00*, m10=-m01*) => only
//   ai,br flip sign with h; h = lane-parity ^ compile-time r-parity =>
//   no per-element selects. U_{Q3} absorbed into measurement sign masks.

typedef float v2 __attribute__((ext_vector_type(2)));

// ===== compile-time GF(2) linear algebra on 10-bit indices =====
struct M10 { unsigned row[10]; };
constexpr M10 mident() { M10 m{}; for (int i=0;i<10;++i) m.row[i]=1u<<i; return m; }
constexpr M10 mmul(M10 A, M10 B) {   // (A*B)s = A(Bs); row_i(AB) = xor_{j in row_i(A)} row_j(B)
  M10 C{};
  for (int i=0;i<10;++i){ unsigned x=0; for (int j=0;j<10;++j) if ((A.row[i]>>j)&1u) x ^= B.row[j]; C.row[i]=x; }
  return C;
}
constexpr M10 cnotT(int ctrl, int rng) {     // s -> s ^ s_cb*e_tb  (self-inverse)
  const int tgt = (ctrl + rng) % 10;
  const int cb = 9 - ctrl, tb = 9 - tgt;
  M10 m = mident(); m.row[tb] = (1u<<tb)|(1u<<cb); return m;
}
// block applied ctrl=0..9 sequentially: psi_out(s) = psi_in(T0*T1*...*T9 s)
constexpr M10 blockPinv(int rng) { M10 m = cnotT(0,rng); for (int c=1;c<10;++c) m = mmul(m, cnotT(c,rng)); return m; }
constexpr M10 blockP(int rng)    { M10 m = cnotT(9,rng); for (int c=8;c>=0;--c) m = mmul(m, cnotT(c,rng)); return m; }
constexpr unsigned mcol(M10 A, int c) { unsigned x=0; for (int i=0;i<10;++i) x |= ((A.row[i]>>c)&1u)<<i; return x; }
constexpr int par(unsigned x){ int p=0; for (int i=0;i<10;++i) p ^= (int)((x>>i)&1u); return p; }
constexpr int topbit4(int x){ int b=0; for (int i=1;i<4;++i) if (x>>i) b=i; return 1<<b; }

constexpr M10 Q1  = blockP(1);
constexpr M10 Q1i = blockPinv(1);
constexpr M10 Q2  = mmul(blockP(2), Q1);
constexpr M10 Q2i = mmul(Q1i, blockPinv(2));
constexpr M10 Q3  = mmul(blockP(3), Q2);

// compile-time sanity: inverses and pairing duality parity(m & v) == 1
static_assert(mmul(Q1, Q1i).row[0]==1u && mmul(Q1,Q1i).row[9]==(1u<<9), "inv1");
static_assert(mmul(Q2, Q2i).row[0]==1u && mmul(Q2,Q2i).row[7]==(1u<<7), "inv2");
static_assert(par(mcol(Q1i,0)&Q1.row[0]) && par(mcol(Q1i,5)&Q1.row[5]) && par(mcol(Q1i,9)&Q1.row[9]), "dual1");
static_assert(par(mcol(Q2i,0)&Q2.row[0]) && par(mcol(Q2i,4)&Q2.row[4]) && par(mcol(Q2i,9)&Q2.row[9]), "dual2");

// ===== cross-lane xor =====
template<int CTRL>
__device__ __forceinline__ float dppf(float v) {
  return __int_as_float(__builtin_amdgcn_update_dpp(
      0, __float_as_int(v), CTRL, 0xF, 0xF, true));
}

// arbitrary lane-xor mask (0..63): DPP where cheap, ds_swizzle <=31, bpermute >=32
template<int MASK>
__device__ __forceinline__ float xany(float v, int baddr) {
  constexpr int QC[4] = {0, 0xB1, 0x4E, 0x1B};
  if constexpr (MASK == 0) return v;
  else if constexpr (MASK <= 3) return dppf<QC[MASK]>(v);
  else if constexpr (MASK == 4) return dppf<0x141>(dppf<0x1B>(v));     // xor7 o xor3
  else if constexpr (MASK == 8) return dppf<0x128>(v);                 // row_ror:8
  else if constexpr (MASK >= 9 && MASK <= 11) return dppf<QC[MASK&3]>(dppf<0x128>(v));
  else if constexpr (MASK < 32) return __int_as_float(__builtin_amdgcn_ds_swizzle(__float_as_int(v), (MASK<<10)|0x1F));
  else return __int_as_float(__builtin_amdgcn_ds_bpermute(baddr, __float_as_int(v)));
}
template<int MASK>
__device__ __forceinline__ v2 xany2(v2 v, int baddr) {
  v2 r; r.x = xany<MASK>(v.x, baddr); r.y = xany<MASK>(v.y, baddr); return r;
}

// pow2-only xor (reductions)
template<int LM>
__device__ __forceinline__ float xshfl(float v) {
  if constexpr (LM == 1) return dppf<0xB1>(v);
  else if constexpr (LM == 2) return dppf<0x4E>(v);
  else if constexpr (LM == 4) return dppf<0x141>(dppf<0x1B>(v));
  else if constexpr (LM == 8) return dppf<0x128>(v);
  else if constexpr (LM == 16) return __int_as_float(__builtin_amdgcn_ds_swizzle(__float_as_int(v), 0x401F));
  else return __shfl_xor(v, 32);
}

// multi-value funnel stage: NP pairs (i, i+NP) across lane bit B
template<int B, int NP>
__device__ __forceinline__ void fstage(float* p, int lane) {
  #pragma unroll
  for (int i = 0; i < NP; ++i) {
    const float send = (lane & B) ? p[i] : p[i + NP];
    const float recv = xshfl<B>(send);
    const float keep = (lane & B) ? p[i + NP] : p[i];
    p[i] = keep + recv;
  }
}
constexpr int holder_lane45(int v) {
  const int a = v >= 24; int r = v - 24 * a;
  const int b = r >= 12; r -= 12 * b;
  const int c = r >= 6;  r -= 6 * c;
  const int d = r >= 3;  r -= 3 * d;
  const int e = r >= 2;  r -= 2 * e;
  return a | (b << 1) | (c << 2) | (d << 3) | (e << 4) | (r << 5);
}
constexpr int holder_lane10(int v) {
  const int a = v >= 5; int r = v - 5 * a;
  const int b = r >= 3; r -= 3 * b;
  const int c = r >= 2; r -= 2 * c;
  return a | (b << 1) | (c << 2) | (r << 3);
}

__device__ __forceinline__ float rfl(float x) {
  return __int_as_float(__builtin_amdgcn_readfirstlane(__float_as_int(x)));
}
#define RLg(g_, x_) __int_as_float(__builtin_amdgcn_readlane(__float_as_int(x_), (g_)))

__device__ __forceinline__ float fast_tanh(float x) {
  return 1.0f - 2.0f / (__expf(2.0f * x) + 1.0f);
}
__device__ __forceinline__ v2 sneg(v2 a) {       // i*a: (re,im)->(-im,re)
  v2 r; r.x = -a.y; r.y = a.x; return r;
}

// ===== general conjugated gate: pair-mask M, indicator-mask V (10-bit) =====
// coeffs: m00=(ar,ai), m01=(br,bi); m11=conj(m00), m10=-conj(m01).
// h(s)=0: out = ar*a + ai*sneg(a) + br*p + bi*sneg(p)
// h(s)=1: out = ar*a - ai*sneg(a) - br*p + bi*sneg(p)
template<int M, int V>
__device__ __forceinline__ void gate_g(v2 (&st)[16], int lane,
                                       float ar, float ai, float br, float bi) {
  constexpr int MR = M & 15, ML = (M >> 4) & 63;
  constexpr int VR = V & 15, VL = (V >> 4) & 63;
  bool hl = false;
  if constexpr (VL != 0) hl = (__builtin_popcount(lane & VL) & 1) != 0;
  const float aiX = hl ? -ai : ai;
  const float brX = hl ? -br : br;
  int baddr = 0;
  if constexpr (ML >= 32) baddr = (lane ^ ML) << 2;
  if constexpr (MR == 0) {
    #pragma unroll
    for (int r = 0; r < 16; ++r) {
      const v2 p = xany2<ML>(st[r], baddr);
      const v2 a = st[r];
      if ((__builtin_popcount(r & VR) & 1) == 0)
        st[r] = ar*a + aiX*sneg(a) + brX*p + bi*sneg(p);
      else
        st[r] = ar*a - aiX*sneg(a) - brX*p + bi*sneg(p);
    }
  } else {
    constexpr int HB = topbit4(MR);
    #pragma unroll
    for (int r = 0; r < 16; ++r) {
      if ((r & HB) == 0) {
        const int r1 = r ^ MR;
        v2 pa, pb;
        if constexpr (ML == 0) { pa = st[r1]; pb = st[r]; }
        else { pa = xany2<ML>(st[r1], baddr); pb = xany2<ML>(st[r], baddr); }
        const v2 a = st[r], b = st[r1];
        if ((__builtin_popcount(r & VR) & 1) == 0)
          st[r] = ar*a + aiX*sneg(a) + brX*pa + bi*sneg(pa);
        else
          st[r] = ar*a - aiX*sneg(a) - brX*pa + bi*sneg(pa);
        if ((__builtin_popcount(r1 & VR) & 1) == 0)
          st[r1] = ar*b + aiX*sneg(b) + brX*pb + bi*sneg(pb);
        else
          st[r1] = ar*b - aiX*sneg(b) - brX*pb + bi*sneg(pb);
      }
    }
  }
}

// half_ang decomposition (unchanged): C(lane) + d[j]*z_j(r) + e[ij]*z_i(r)z_j(r)
template<int I, int J>
__device__ __forceinline__ void pair_accum(float t, int lane, float& Cc,
                                           float (&dcf)[4], float (&ecf)[6]) {
  if constexpr (J <= 5) {
    const bool diff = (((lane >> (5 - I)) ^ (lane >> (5 - J))) & 1) != 0;
    Cc += diff ? -t : t;
  } else if constexpr (I <= 5) {
    const bool b = ((lane >> (5 - I)) & 1) != 0;
    dcf[J - 6] += b ? -t : t;
  } else {
    constexpr int eb = (I == 6) ? 0 : (I == 7) ? 3 : 5;
    ecf[eb + (J - I - 1)] = t;
  }
}
#define PACC(v_, i_, j_) pair_accum<i_, j_>(RLg(holder_lane45(v_), tl), lane, Cc, dcoef, ecoef);

#define GATE0(g_, q_) gate_g<(1<<(9-(q_))), (1<<(9-(q_)))>(st, lane, \
    RLg(g_,Mr00), RLg(g_,Mi00), RLg(g_,Mr01), RLg(g_,Mi01));
#define GATE1(g_, q_) gate_g<(int)mcol(Q1i,9-(q_)), (int)Q1.row[9-(q_)]>(st, lane, \
    RLg(g_,Mr00), RLg(g_,Mi00), RLg(g_,Mr01), RLg(g_,Mi01));
#define GATE2(g_, q_) gate_g<(int)mcol(Q2i,9-(q_)), (int)Q2.row[9-(q_)]>(st, lane, \
    RLg(g_,Mr00), RLg(g_,Mi00), RLg(g_,Mr01), RLg(g_,Mi01));

extern "C" __global__ void __launch_bounds__(256, 2)
qhl_kernel(const float* __restrict__ c_kt, const float* __restrict__ dc_kt,
           const float* __restrict__ vw,  const float* __restrict__ w_proj,
           const float* __restrict__ b_proj, const float* __restrict__ log_alpha,
           float* __restrict__ out) {
  const int wave = threadIdx.x >> 6;
  const int lane = threadIdx.x & 63;
  const int bid  = blockIdx.x * 4 + wave;

  const float* c   = c_kt  + (size_t)bid * 1280;
  const float* dcp = dc_kt + (size_t)bid * 1280;

  // ---- per-lane gate-matrix precompute: lane g -> gate (l=g/10, q=g%10)
  // only m00=(ar,ai), m01=(br,bi) needed (SU(2) symmetry supplies the rest)
  float Mr00, Mi00, Mr01, Mi01;
  {
    const int g = lane < 30 ? lane : 0;
    const int l = g / 10, q = g - l * 10;
    const float w0 = vw[g*3+0], w1 = vw[g*3+1], w2 = vw[g*3+2];
    float cY, sY; __sincosf(0.5f*w1, &sY, &cY);
    float ca, sa; __sincosf(0.5f*(w0+w2), &sa, &ca);
    float cb, sb; __sincosf(0.5f*(w0-w2), &sb, &cb);
    const float r00r =  cY*ca, r00i = -cY*sa, r01r = -sY*cb, r01i = -sY*sb;
    if (l == 0) {
      Mr00 = r00r; Mi00 = r00i; Mr01 = r01r; Mi01 = r01i;
    } else {
      const float thq = c[1270 + q], phq = dcp[1270 + q];
      float cy, sy; __sincosf(0.25f * thq, &sy, &cy);
      float cz, sz; __sincosf(0.25f * phq, &sz, &cz);
      const float e00r =  cy*cz, e00i = -cy*sz, e01r = -sy*cz, e01i =  sy*sz;
      const float e10r =  sy*cz, e10i =  sy*sz, e11r =  cy*cz, e11i =  cy*sz;
      Mr00 = r00r*e00r - r00i*e00i + r01r*e10r - r01i*e10i;
      Mi00 = r00r*e00i + r00i*e00r + r01r*e10i + r01i*e10r;
      Mr01 = r00r*e01r - r00i*e01i + r01r*e11r - r01i*e11i;
      Mi01 = r00r*e01i + r00i*e01r + r01r*e11i + r01i*e11r;
    }
  }

  // ---- correlation rows packed as (t=lane, t=lane+64) float2 pairs ----
  v2 ym[10];
  {
    const float2* c0 = (const float2*)(c   + lane * 10);
    const float2* d0 = (const float2*)(dcp + lane * 10);
    const float2* c1 = (const float2*)(c   + (lane + 64) * 10);
    const float2* d1 = (const float2*)(dcp + (lane + 64) * 10);
    #pragma unroll
    for (int k = 0; k < 5; ++k) {
      const float2 a0 = c0[k], b0 = d0[k], a1 = c1[k], b1 = d1[k];
      ym[2*k].x   = a0.x + 0.5f * b0.x;  ym[2*k].y   = a1.x + 0.5f * b1.x;
      ym[2*k+1].x = a0.y + 0.5f * b0.y;  ym[2*k+1].y = a1.y + 0.5f * b1.y;
    }
  }

  // ---- row stats via 10-value funnels ----
  {
    float mb[6];
    float m10a[10];
    #pragma unroll
    for (int k = 0; k < 10; ++k) m10a[k] = ym[k].x + ym[k].y;
    #pragma unroll
    for (int i = 0; i < 5; ++i) {
      const float send = (lane & 1) ? m10a[i] : m10a[i + 5];
      const float recv = xshfl<1>(send);
      const float keep = (lane & 1) ? m10a[i + 5] : m10a[i];
      mb[i] = keep + recv;
    }
    mb[5] = 0.0f;
    fstage<2, 3>(mb, lane);
    mb[3] = 0.0f;
    fstage<4, 2>(mb, lane);
    fstage<8, 1>(mb, lane);
    mb[0] += xshfl<16>(mb[0]);
    mb[0] += xshfl<32>(mb[0]);
    mb[0] *= (1.0f / 128.0f);
    #pragma unroll
    for (int k = 0; k < 10; ++k) {
      const float mk = RLg(holder_lane10(k), mb[0]);
      ym[k].x -= mk; ym[k].y -= mk;
    }
    float s10[10];
    #pragma unroll
    for (int k = 0; k < 10; ++k) { const v2 sq = ym[k] * ym[k]; s10[k] = sq.x + sq.y; }
    #pragma unroll
    for (int i = 0; i < 5; ++i) {
      const float send = (lane & 1) ? s10[i] : s10[i + 5];
      const float recv = xshfl<1>(send);
      const float keep = (lane & 1) ? s10[i + 5] : s10[i];
      mb[i] = keep + recv;
    }
    mb[5] = 0.0f;
    fstage<2, 3>(mb, lane);
    mb[3] = 0.0f;
    fstage<4, 2>(mb, lane);
    fstage<8, 1>(mb, lane);
    mb[0] += xshfl<16>(mb[0]);
    mb[0] += xshfl<32>(mb[0]);
    const float rsv = fminf(__builtin_amdgcn_rsqf(mb[0] * (1.0f / 127.0f)), 1e8f);
    #pragma unroll
    for (int k = 0; k < 10; ++k) {
      const float rk = RLg(holder_lane10(k), rsv);
      ym[k].x *= rk; ym[k].y *= rk;
    }
  }

  // ---- 45 pair dots via one 48-slot funnel; tanh lane-parallel ----
  const float expA = rfl(__expf(log_alpha[0]));
  float Cc = 0.0f, dcoef[4] = {0, 0, 0, 0}, ecoef[6];
  float tl;
  {
    constexpr int PI_[45] = {0,0,0,0,0,0,0,0,0, 1,1,1,1,1,1,1,1, 2,2,2,2,2,2,2,
                             3,3,3,3,3,3, 4,4,4,4,4, 5,5,5,5, 6,6,6, 7,7, 8};
    constexpr int PJ_[45] = {1,2,3,4,5,6,7,8,9, 2,3,4,5,6,7,8,9, 3,4,5,6,7,8,9,
                             4,5,6,7,8,9, 5,6,7,8,9, 6,7,8,9, 7,8,9, 8,9, 9};
    float p[48];
    #pragma unroll
    for (int v = 0; v < 45; ++v) {
      const v2 pr = ym[PI_[v]] * ym[PJ_[v]];
      p[v] = pr.x + pr.y;
    }
    p[45] = 0.0f; p[46] = 0.0f; p[47] = 0.0f;
    fstage<1, 24>(p, lane);
    fstage<2, 12>(p, lane);
    fstage<4, 6>(p, lane);
    fstage<8, 3>(p, lane);
    p[3] = 0.0f;
    fstage<16, 2>(p, lane);
    fstage<32, 1>(p, lane);
    const float sc = expA * (1.0f / 127.0f);
    tl = -1.5707963267948966f * fast_tanh(p[0] * sc);
  }
  PACC(0,0,1) PACC(1,0,2) PACC(2,0,3) PACC(3,0,4) PACC(4,0,5) PACC(5,0,6) PACC(6,0,7) PACC(7,0,8) PACC(8,0,9)
  PACC(9,1,2) PACC(10,1,3) PACC(11,1,4) PACC(12,1,5) PACC(13,1,6) PACC(14,1,7) PACC(15,1,8) PACC(16,1,9)
  PACC(17,2,3) PACC(18,2,4) PACC(19,2,5) PACC(20,2,6) PACC(21,2,7) PACC(22,2,8) PACC(23,2,9)
  PACC(24,3,4) PACC(25,3,5) PACC(26,3,6) PACC(27,3,7) PACC(28,3,8) PACC(29,3,9)
  PACC(30,4,5) PACC(31,4,6) PACC(32,4,7) PACC(33,4,8) PACC(34,4,9)
  PACC(35,5,6) PACC(36,5,7) PACC(37,5,8) PACC(38,5,9)
  PACC(39,6,7) PACC(40,6,8) PACC(41,6,9)
  PACC(42,7,8) PACC(43,7,9)
  PACC(44,8,9)

  // ---- encoding angles: wave-uniform -> SGPRs ----
  float th[10], ph[10];
  #pragma unroll
  for (int q = 0; q < 10; ++q) {
    th[q] = rfl(c[1270 + q]);
    ph[q] = rfl(dcp[1270 + q]);
  }

  // ---- per-lane R product: lane r computes R_r for qubits 6..9 ----
  float Rr_l, Ri_l;
  {
    const int rr = lane & 15;
    float prr = 1.0f, pri = 0.0f;
    #pragma unroll
    for (int t = 0; t < 4; ++t) {
      float cy, sy; __sincosf(0.5f * th[6 + t], &sy, &cy);
      float cz, sz; __sincosf(0.5f * ph[6 + t], &sz, &cz);
      const bool b = ((rr >> (3 - t)) & 1) != 0;
      const float fr = b ? sy * cz : cy * cz;
      const float fi = b ? sy * sz : -cy * sz;
      const float nr = prr * fr - pri * fi;
      pri = prr * fi + pri * fr;
      prr = nr;
    }
    Rr_l = prr; Ri_l = pri;
  }

  // ---- closed-form initial state: (prod_q RZ(ph)RY(th)|0>) * e^{i h} ----
  v2 st[16];
  {
    v2 L; L.x = 1.0f; L.y = 0.0f;
    #pragma unroll
    for (int q = 0; q < 6; ++q) {
      float cy, sy; __sincosf(0.5f * th[q], &sy, &cy);
      float cz, sz; __sincosf(0.5f * ph[q], &sz, &cz);
      const bool b = ((lane >> (5 - q)) & 1) != 0;
      const float zr = b ? sy * cz : cy * cz;
      const float zi = b ? sy * sz : -cy * sz;
      L = zr * L + zi * sneg(L);
    }
    #pragma unroll
    for (int r = 0; r < 16; ++r) {
      const int b3 = (r >> 3) & 1, b2 = (r >> 2) & 1, b1 = (r >> 1) & 1, b0 = r & 1;
      const float Rr = RLg(r, Rr_l);
      const float Ri = RLg(r, Ri_l);
      float h = Cc;
      h += b3 ? -dcoef[0] : dcoef[0];
      h += b2 ? -dcoef[1] : dcoef[1];
      h += b1 ? -dcoef[2] : dcoef[2];
      h += b0 ? -dcoef[3] : dcoef[3];
      h += (b3 ^ b2) ? -ecoef[0] : ecoef[0];
      h += (b3 ^ b1) ? -ecoef[1] : ecoef[1];
      h += (b3 ^ b0) ? -ecoef[2] : ecoef[2];
      h += (b2 ^ b1) ? -ecoef[3] : ecoef[3];
      h += (b2 ^ b0) ? -ecoef[4] : ecoef[4];
      h += (b1 ^ b0) ? -ecoef[5] : ecoef[5];
      float sn, cs; __sincosf(h, &sn, &cs);
      const v2 p = cs * L + sn * sneg(L);
      st[r] = Rr * p + Ri * sneg(p);
    }
  }

  // ---- layer 0 (standard frame) ----
  GATE0(0,0) GATE0(1,1) GATE0(2,2) GATE0(3,3) GATE0(4,4)
  GATE0(5,5) GATE0(6,6) GATE0(7,7) GATE0(8,8) GATE0(9,9)
  // ---- layer 1 conjugated by Q1 (CNOT block rng=1 folded) ----
  GATE1(10,0) GATE1(11,1) GATE1(12,2) GATE1(13,3) GATE1(14,4)
  GATE1(15,5) GATE1(16,6) GATE1(17,7) GATE1(18,8) GATE1(19,9)
  // ---- layer 2 conjugated by Q2 (blocks rng=1,2 folded) ----
  GATE2(20,0) GATE2(21,1) GATE2(22,2) GATE2(23,3) GATE2(24,4)
  GATE2(25,5) GATE2(26,6) GATE2(27,7) GATE2(28,8) GATE2(29,9)
  // (CNOT block rng=3 folded into measurement sign masks via Q3)

  // ---- measurement: Z expvals with Q3-row parities, funnel, projection ----
  float e[10] = {0,0,0,0,0,0,0,0,0,0};
  #pragma unroll
  for (int r = 0; r < 16; ++r) {
    const v2 sq = st[r] * st[r];
    const float pp = sq.x + sq.y;
    #pragma unroll
    for (int q = 0; q < 10; ++q) {
      const bool s = (__builtin_popcount(r & (int)(Q3.row[9-q] & 15u)) & 1) != 0;
      e[q] += s ? -pp : pp;
    }
  }
  float mv[10];
  #pragma unroll
  for (int q = 0; q < 10; ++q) {
    const int wl = (int)((Q3.row[9-q] >> 4) & 63u);
    const bool sl = wl ? ((__builtin_popcount(lane & wl) & 1) != 0) : false;
    mv[q] = sl ? -e[q] : e[q];
  }
  {
    float fb[6];
    #pragma unroll
    for (int i = 0; i < 5; ++i) {
      const float send = (lane & 1) ? mv[i] : mv[i + 5];
      const float recv = xshfl<1>(send);
      const float keep = (lane & 1) ? mv[i + 5] : mv[i];
      fb[i] = keep + recv;
    }
    fb[5] = 0.0f;
    fstage<2, 3>(fb, lane);
    fb[3] = 0.0f;
    fstage<4, 2>(fb, lane);
    fstage<8, 1>(fb, lane);
    fb[0] += xshfl<16>(fb[0]);
    fb[0] += xshfl<32>(fb[0]);
    float ev[10];
    #pragma unroll
    for (int k = 0; k < 10; ++k) ev[k] = RLg(holder_lane10(k), fb[0]);
    if (lane < 3) {
      float acc = b_proj[lane];
      #pragma unroll
      for (int i = 0; i < 10; ++i) acc += w_proj[lane * 10 + i] * ev[i];
      out[(size_t)bid * 3 + lane] = acc;
    }
  }
}

extern "C" void kernel_launch(void* const* d_in, const int* in_sizes, int n_in,
                              void* d_out, int out_size, void* d_ws, size_t ws_size,
                              hipStream_t stream) {
  (void)in_sizes; (void)n_in; (void)d_ws; (void)ws_size; (void)out_size;
  const float* c_kt      = (const float*)d_in[0];
  const float* dc_kt     = (const float*)d_in[1];
  const float* vw        = (const float*)d_in[2];
  const float* w_proj    = (const float*)d_in[3];
  const float* b_proj    = (const float*)d_in[4];
  const float* log_alpha = (const float*)d_in[5];
  float* out = (float*)d_out;
  // 4096 batch elems, 1 wave each, 4 waves per 256-thread block
  qhl_kernel<<<dim3(1024), dim3(256), 0, stream>>>(c_kt, dc_kt, vw, w_proj,
                                                   b_proj, log_alpha, out);
}